// Round 14
// baseline (56.091 us; speedup 1.0000x reference)
//
#include <hip/hip_runtime.h>
#include <math.h>

#define TPB 256
#define TWO_PI_F 6.283185307179586f

// State layout: one wave holds TWO batch elements, 1024 amplitudes each:
// s = (lane << 4) | r, r=0..15 in re0/im0[16] and re1/im1[16].
// Qubit w -> state bit (9-w). w<=5: lane bit (5-w). w>=6: local bit (9-w).
// Duo structure: every exchange phase issues BOTH elements' cross-lane ops
// before either compute -> in-wave ILP hides exchange latency.

#define ALLQ(OP) OP(0) OP(1) OP(2) OP(3) OP(4) OP(5) OP(6) OP(7) OP(8) OP(9)
#define ALLQ9(OP) OP(0) OP(1) OP(2) OP(3) OP(4) OP(5) OP(6) OP(7) OP(8)

template<int CTRL>
__device__ __forceinline__ float dppmv(float v) {
    return __builtin_bit_cast(float,
        __builtin_amdgcn_update_dpp(0, __builtin_bit_cast(int, v), CTRL, 0xF, 0xF, true));
}

template<int LM>
__device__ __forceinline__ float lx(float v, int lane) {
    (void)lane;
    if constexpr (LM == 1)       return dppmv<0xB1>(v);
    else if constexpr (LM == 2)  return dppmv<0x4E>(v);
    else if constexpr (LM == 3)  return dppmv<0x1B>(v);
    else if constexpr (LM == 4)  return dppmv<0x1B>(dppmv<0x141>(v));   // 7^3
    else if constexpr (LM == 6)  return dppmv<0xB1>(dppmv<0x141>(v));   // 7^1
    else if constexpr (LM == 8)  return dppmv<0x128>(v);                // ror 8
    else if constexpr (LM == 12) return dppmv<0x1B>(dppmv<0x140>(v));   // 15^3
    else                         return __shfl_xor(v, LM);              // 16,24,32,48,56
}

// constexpr-safe qubit-bit extraction (avoids negative-shift instantiations)
template<int W>
__device__ __forceinline__ int qbit(int lane, int r) {
    if constexpr (W <= 5) return (lane >> (5 - W)) & 1;
    else                  return (r >> (9 - W)) & 1;
}

// ---------------- single-element gates (branch circuits) ----------------

template<int W>
__device__ __forceinline__ void g_ry(float (&re)[16], float (&im)[16], float c, float s, int lane) {
    if constexpr (W <= 5) {
        constexpr int LM = 1 << (5 - W);
        const float ss = ((lane >> (5 - W)) & 1) ? s : -s;
        float pr[16], pi[16];
#pragma unroll
        for (int r = 0; r < 16; ++r) { pr[r] = lx<LM>(re[r], lane); pi[r] = lx<LM>(im[r], lane); }
#pragma unroll
        for (int r = 0; r < 16; ++r) {
            re[r] = fmaf(ss, pr[r], c * re[r]);
            im[r] = fmaf(ss, pi[r], c * im[r]);
        }
    } else {
        constexpr int MK = 1 << (9 - W);
#pragma unroll
        for (int r = 0; r < 16; ++r) {
            if ((r & MK) == 0) {
                const int r1 = r | MK;
                float r0 = re[r], i0 = im[r], r1v = re[r1], i1 = im[r1];
                re[r]  = fmaf(-s, r1v, c * r0);
                im[r]  = fmaf(-s, i1,  c * i0);
                re[r1] = fmaf( s, r0,  c * r1v);
                im[r1] = fmaf( s, i0,  c * i1);
            }
        }
    }
}

template<int W>
__device__ __forceinline__ void g_rx(float (&re)[16], float (&im)[16], float c, float s, int lane) {
    if constexpr (W <= 5) {
        constexpr int LM = 1 << (5 - W);
        float pr[16], pi[16];
#pragma unroll
        for (int r = 0; r < 16; ++r) { pr[r] = lx<LM>(re[r], lane); pi[r] = lx<LM>(im[r], lane); }
#pragma unroll
        for (int r = 0; r < 16; ++r) {
            re[r] = fmaf( s, pi[r], c * re[r]);
            im[r] = fmaf(-s, pr[r], c * im[r]);
        }
    } else {
        constexpr int MK = 1 << (9 - W);
#pragma unroll
        for (int r = 0; r < 16; ++r) {
            if ((r & MK) == 0) {
                const int r1 = r | MK;
                float r0 = re[r], i0 = im[r], r1v = re[r1], i1 = im[r1];
                re[r]  = fmaf( s, i1,  c * r0);
                im[r]  = fmaf(-s, r1v, c * i0);
                re[r1] = fmaf( s, i0,  c * r1v);
                im[r1] = fmaf(-s, r0,  c * i1);
            }
        }
    }
}

template<int C, int T>
__device__ __forceinline__ void g_crz(float (&re)[16], float (&im)[16], float c, float s, int lane) {
#pragma unroll
    for (int r = 0; r < 16; ++r) {
        const int cb = qbit<C>(lane, r);
        const int tb = qbit<T>(lane, r);
        const float cc  = cb ? c : 1.f;
        const float sp2 = cb ? (tb ? s : -s) : 0.f;
        float rr = re[r], ii = im[r];
        re[r] = cc * rr - sp2 * ii;
        im[r] = cc * ii + sp2 * rr;
    }
}

// ry(q0) ⊗ ry(q1) fused (branch gating)
__device__ __forceinline__ void g_ry2_01(float (&re)[16], float (&im)[16],
                                         float c0, float s0, float c1, float s1, int lane) {
    float ar[16], ai[16], br[16], bi[16], cr2[16], ci2[16];
#pragma unroll
    for (int r = 0; r < 16; ++r) { ar[r] = lx<32>(re[r], lane); ai[r] = lx<32>(im[r], lane); }
#pragma unroll
    for (int r = 0; r < 16; ++r) { br[r] = lx<16>(re[r], lane); bi[r] = lx<16>(im[r], lane); }
#pragma unroll
    for (int r = 0; r < 16; ++r) { cr2[r] = lx<48>(re[r], lane); ci2[r] = lx<48>(im[r], lane); }
    const float sg0 = ((lane >> 5) & 1) ? s0 : -s0;
    const float sg1 = ((lane >> 4) & 1) ? s1 : -s1;
    const float k0 = c0 * c1, k1 = c1 * sg0, k2 = c0 * sg1, k3 = sg0 * sg1;
#pragma unroll
    for (int r = 0; r < 16; ++r) {
        float o_r = k0 * re[r];
        o_r = fmaf(k1, ar[r], o_r); o_r = fmaf(k2, br[r], o_r); o_r = fmaf(k3, cr2[r], o_r);
        float o_i = k0 * im[r];
        o_i = fmaf(k1, ai[r], o_i); o_i = fmaf(k2, bi[r], o_i); o_i = fmaf(k3, ci2[r], o_i);
        re[r] = o_r; im[r] = o_i;
    }
}

// rx(q0) ⊗ rx(q1) fused (branch gating)
__device__ __forceinline__ void g_rx2_01(float (&re)[16], float (&im)[16],
                                         float c0, float s0, float c1, float s1, int lane) {
    float ar[16], ai[16], br[16], bi[16], cr2[16], ci2[16];
#pragma unroll
    for (int r = 0; r < 16; ++r) { ar[r] = lx<32>(re[r], lane); ai[r] = lx<32>(im[r], lane); }
#pragma unroll
    for (int r = 0; r < 16; ++r) { br[r] = lx<16>(re[r], lane); bi[r] = lx<16>(im[r], lane); }
#pragma unroll
    for (int r = 0; r < 16; ++r) { cr2[r] = lx<48>(re[r], lane); ci2[r] = lx<48>(im[r], lane); }
    const float k0 = c0 * c1, kA = c1 * s0, kB = c0 * s1, kC = s0 * s1;
#pragma unroll
    for (int r = 0; r < 16; ++r) {
        float rr = re[r], ii = im[r];
        float o_r = k0 * rr;
        o_r = fmaf(kA, ai[r], o_r); o_r = fmaf(kB, bi[r], o_r); o_r = fmaf(-kC, cr2[r], o_r);
        float o_i = k0 * ii;
        o_i = fmaf(-kA, ar[r], o_i); o_i = fmaf(-kB, br[r], o_i); o_i = fmaf(-kC, ci2[r], o_i);
        re[r] = o_r; im[r] = o_i;
    }
}

// full-wave reduce (sum)
__device__ __forceinline__ float wred(float v, int lane) {
    v += lx<1>(v, lane); v += lx<2>(v, lane); v += lx<4>(v, lane);
    v += lx<8>(v, lane); v += lx<16>(v, lane); v += lx<32>(v, lane);
    return v;
}

// folded measurement, single element (branch gating)
__device__ float meas_fold(const float (&re)[16], const float (&im)[16],
                           const float* __restrict__ V, int lane) {
    float oacc = 0.f;
    float n2[16], n2s = 0.f;
#pragma unroll
    for (int r = 0; r < 16; ++r) { n2[r] = fmaf(re[r], re[r], im[r] * im[r]); n2s += n2[r]; }

#define M_LANE(w, LM_) { \
        float pr[16], pi[16]; \
        _Pragma("unroll") \
        for (int r = 0; r < 16; ++r) { pr[r] = lx<LM_>(re[r], lane); pi[r] = lx<LM_>(im[r], lane); } \
        float xa = 0.f, ya = 0.f; \
        _Pragma("unroll") \
        for (int r = 0; r < 16; ++r) { \
            xa = fmaf(re[r], pr[r], xa); xa = fmaf(im[r], pi[r], xa); \
            ya = fmaf(re[r], pi[r], ya); ya = fmaf(-im[r], pr[r], ya); \
        } \
        const float sg = ((lane >> (5 - w)) & 1) ? -1.f : 1.f; \
        oacc = fmaf(xa, V[w], oacc); \
        oacc = fmaf(sg * ya, V[10 + w], oacc); \
        oacc = fmaf(sg * n2s, V[20 + w], oacc); }
    M_LANE(0, 32) M_LANE(1, 16) M_LANE(2, 8) M_LANE(3, 4) M_LANE(4, 2) M_LANE(5, 1)
#undef M_LANE

#define M_REG(w, MK) { \
        float xa = 0.f, ya = 0.f, za = 0.f; \
        _Pragma("unroll") \
        for (int r = 0; r < 16; ++r) { \
            if ((r & MK) == 0) { \
                const int r1 = r | MK; \
                xa = fmaf(re[r], re[r1], xa); xa = fmaf(im[r], im[r1], xa); \
                ya = fmaf(re[r], im[r1], ya); ya = fmaf(-im[r], re[r1], ya); \
                za += n2[r] - n2[r1]; \
            } } \
        oacc = fmaf(2.f * xa, V[w], oacc); \
        oacc = fmaf(2.f * ya, V[10 + w], oacc); \
        oacc = fmaf(za, V[20 + w], oacc); }
    M_REG(6, 8) M_REG(7, 4) M_REG(8, 2) M_REG(9, 1)
#undef M_REG
    return oacc;
}

__device__ __forceinline__ void init_zero(float (&re)[16], float (&im)[16], int lane) {
#pragma unroll
    for (int r = 0; r < 16; ++r) { re[r] = 0.f; im[r] = 0.f; }
    if (lane == 0) re[0] = 1.f;
}

// ---------------- duo gates (main path) ----------------

template<int W>
__device__ __forceinline__ void g_ry_d(float (&re0)[16], float (&im0)[16],
                                       float (&re1)[16], float (&im1)[16],
                                       float cA, float sA, float cB, float sB, int lane) {
    if constexpr (W <= 5) {
        constexpr int LM = 1 << (5 - W);
        const int bit = (lane >> (5 - W)) & 1;
        const float ssA = bit ? sA : -sA;
        const float ssB = bit ? sB : -sB;
        float p0r[16], p0i[16], p1r[16], p1i[16];
#pragma unroll
        for (int r = 0; r < 16; ++r) { p0r[r] = lx<LM>(re0[r], lane); p0i[r] = lx<LM>(im0[r], lane); }
#pragma unroll
        for (int r = 0; r < 16; ++r) { p1r[r] = lx<LM>(re1[r], lane); p1i[r] = lx<LM>(im1[r], lane); }
#pragma unroll
        for (int r = 0; r < 16; ++r) {
            re0[r] = fmaf(ssA, p0r[r], cA * re0[r]);
            im0[r] = fmaf(ssA, p0i[r], cA * im0[r]);
        }
#pragma unroll
        for (int r = 0; r < 16; ++r) {
            re1[r] = fmaf(ssB, p1r[r], cB * re1[r]);
            im1[r] = fmaf(ssB, p1i[r], cB * im1[r]);
        }
    } else {
        constexpr int MK = 1 << (9 - W);
#pragma unroll
        for (int r = 0; r < 16; ++r) {
            if ((r & MK) == 0) {
                const int r1 = r | MK;
                float a = re0[r], b = im0[r], c2 = re0[r1], d = im0[r1];
                re0[r]  = fmaf(-sA, c2, cA * a);
                im0[r]  = fmaf(-sA, d,  cA * b);
                re0[r1] = fmaf( sA, a,  cA * c2);
                im0[r1] = fmaf( sA, b,  cA * d);
                float e = re1[r], f = im1[r], g = re1[r1], h = im1[r1];
                re1[r]  = fmaf(-sB, g, cB * e);
                im1[r]  = fmaf(-sB, h, cB * f);
                re1[r1] = fmaf( sB, e, cB * g);
                im1[r1] = fmaf( sB, f, cB * h);
            }
        }
    }
}

template<int A, int Bq, bool YY>
__device__ __forceinline__ void g_xy_d(float (&re0)[16], float (&im0)[16],
                                       float (&re1)[16], float (&im1)[16],
                                       float cA, float sA, float cB, float sB, int lane) {
    constexpr int bpA = 9 - A, bpB = 9 - Bq;
    constexpr int LM   = ((bpA >= 4) ? (1 << (bpA - 4)) : 0) | ((bpB >= 4) ? (1 << (bpB - 4)) : 0);
    constexpr int LOCM = ((bpA < 4) ? (1 << bpA) : 0) | ((bpB < 4) ? (1 << bpB) : 0);
    float p0r[16], p0i[16], p1r[16], p1i[16];
#pragma unroll
    for (int r = 0; r < 16; ++r) {
        float vr = re0[r ^ LOCM], vi = im0[r ^ LOCM];
        if constexpr (LM != 0) { p0r[r] = lx<LM>(vr, lane); p0i[r] = lx<LM>(vi, lane); }
        else                   { p0r[r] = vr; p0i[r] = vi; }
    }
#pragma unroll
    for (int r = 0; r < 16; ++r) {
        float vr = re1[r ^ LOCM], vi = im1[r ^ LOCM];
        if constexpr (LM != 0) { p1r[r] = lx<LM>(vr, lane); p1i[r] = lx<LM>(vi, lane); }
        else                   { p1r[r] = vr; p1i[r] = vi; }
    }
#pragma unroll
    for (int r = 0; r < 16; ++r) {
        float sgA, sgB;
        if constexpr (YY) {
            const int bA = qbit<A>(lane, r);
            const int bB = qbit<Bq>(lane, r);
            sgA = (bA == bB) ? -sA : sA;
            sgB = (bA == bB) ? -sB : sB;
        } else { sgA = sA; sgB = sB; }
        {
            float rr = re0[r], ii = im0[r];
            re0[r] = fmaf( sgA, p0i[r], cA * rr);
            im0[r] = fmaf(-sgA, p0r[r], cA * ii);
        }
        {
            float rr = re1[r], ii = im1[r];
            re1[r] = fmaf( sgB, p1i[r], cB * rr);
            im1[r] = fmaf(-sgB, p1r[r], cB * ii);
        }
    }
}

template<int W>
__device__ __forceinline__ void g_u1_d(float (&re0)[16], float (&im0)[16],
                                       float (&re1)[16], float (&im1)[16],
                                       const float* U0, const float* U1, int lane) {
    if constexpr (W <= 5) {
        constexpr int LM = 1 << (5 - W);
        const int side = (lane >> (5 - W)) & 1;
        const float aR0 = side ? U0[6] : U0[0], aI0 = side ? U0[7] : U0[1];
        const float bR0 = side ? U0[4] : U0[2], bI0 = side ? U0[5] : U0[3];
        const float aR1 = side ? U1[6] : U1[0], aI1 = side ? U1[7] : U1[1];
        const float bR1 = side ? U1[4] : U1[2], bI1 = side ? U1[5] : U1[3];
        float p0r[16], p0i[16], p1r[16], p1i[16];
#pragma unroll
        for (int r = 0; r < 16; ++r) { p0r[r] = lx<LM>(re0[r], lane); p0i[r] = lx<LM>(im0[r], lane); }
#pragma unroll
        for (int r = 0; r < 16; ++r) { p1r[r] = lx<LM>(re1[r], lane); p1i[r] = lx<LM>(im1[r], lane); }
#pragma unroll
        for (int r = 0; r < 16; ++r) {
            float rr = re0[r], ii = im0[r];
            float nr = aR0 * rr; nr = fmaf(-aI0, ii, nr); nr = fmaf(bR0, p0r[r], nr); nr = fmaf(-bI0, p0i[r], nr);
            float ni = aR0 * ii; ni = fmaf( aI0, rr, ni); ni = fmaf(bR0, p0i[r], ni); ni = fmaf( bI0, p0r[r], ni);
            re0[r] = nr; im0[r] = ni;
        }
#pragma unroll
        for (int r = 0; r < 16; ++r) {
            float rr = re1[r], ii = im1[r];
            float nr = aR1 * rr; nr = fmaf(-aI1, ii, nr); nr = fmaf(bR1, p1r[r], nr); nr = fmaf(-bI1, p1i[r], nr);
            float ni = aR1 * ii; ni = fmaf( aI1, rr, ni); ni = fmaf(bR1, p1i[r], ni); ni = fmaf( bI1, p1r[r], ni);
            re1[r] = nr; im1[r] = ni;
        }
    } else {
        constexpr int MK = 1 << (9 - W);
#pragma unroll
        for (int r = 0; r < 16; ++r) {
            if ((r & MK) == 0) {
                const int r1 = r | MK;
                {
                    float r0 = re0[r], i0 = im0[r], r1v = re0[r1], i1 = im0[r1];
                    float a = U0[0]*r0; a = fmaf(-U0[1], i0, a); a = fmaf(U0[2], r1v, a); a = fmaf(-U0[3], i1, a);
                    float b = U0[0]*i0; b = fmaf( U0[1], r0, b); b = fmaf(U0[2], i1,  b); b = fmaf( U0[3], r1v, b);
                    float c = U0[4]*r0; c = fmaf(-U0[5], i0, c); c = fmaf(U0[6], r1v, c); c = fmaf(-U0[7], i1, c);
                    float d = U0[4]*i0; d = fmaf( U0[5], r0, d); d = fmaf(U0[6], i1,  d); d = fmaf( U0[7], r1v, d);
                    re0[r] = a; im0[r] = b; re0[r1] = c; im0[r1] = d;
                }
                {
                    float r0 = re1[r], i0 = im1[r], r1v = re1[r1], i1 = im1[r1];
                    float a = U1[0]*r0; a = fmaf(-U1[1], i0, a); a = fmaf(U1[2], r1v, a); a = fmaf(-U1[3], i1, a);
                    float b = U1[0]*i0; b = fmaf( U1[1], r0, b); b = fmaf(U1[2], i1,  b); b = fmaf( U1[3], r1v, b);
                    float c = U1[4]*r0; c = fmaf(-U1[5], i0, c); c = fmaf(U1[6], r1v, c); c = fmaf(-U1[7], i1, c);
                    float d = U1[4]*i0; d = fmaf( U1[5], r0, d); d = fmaf(U1[6], i1,  d); d = fmaf( U1[7], r1v, d);
                    re1[r] = a; im1[r] = b; re1[r1] = c; im1[r1] = d;
                }
            }
        }
    }
}

// duo folded measurement; V shared (parameter-only fold vector)
__device__ void meas_fold_d(const float (&re0)[16], const float (&im0)[16],
                            const float (&re1)[16], const float (&im1)[16],
                            const float* __restrict__ V, int lane,
                            float& o0out, float& o1out) {
    float o0 = 0.f, o1 = 0.f;
    float n2s0 = 0.f, n2s1 = 0.f;
#pragma unroll
    for (int r = 0; r < 16; ++r) { n2s0 = fmaf(re0[r], re0[r], n2s0); n2s0 = fmaf(im0[r], im0[r], n2s0); }
#pragma unroll
    for (int r = 0; r < 16; ++r) { n2s1 = fmaf(re1[r], re1[r], n2s1); n2s1 = fmaf(im1[r], im1[r], n2s1); }

#define MD_LANE(w, LM_) { \
        float p0r[16], p0i[16], p1r[16], p1i[16]; \
        _Pragma("unroll") \
        for (int r = 0; r < 16; ++r) { p0r[r] = lx<LM_>(re0[r], lane); p0i[r] = lx<LM_>(im0[r], lane); } \
        _Pragma("unroll") \
        for (int r = 0; r < 16; ++r) { p1r[r] = lx<LM_>(re1[r], lane); p1i[r] = lx<LM_>(im1[r], lane); } \
        float xa0 = 0.f, ya0 = 0.f, xa1 = 0.f, ya1 = 0.f; \
        _Pragma("unroll") \
        for (int r = 0; r < 16; ++r) { \
            xa0 = fmaf(re0[r], p0r[r], xa0); xa0 = fmaf(im0[r], p0i[r], xa0); \
            ya0 = fmaf(re0[r], p0i[r], ya0); ya0 = fmaf(-im0[r], p0r[r], ya0); \
        } \
        _Pragma("unroll") \
        for (int r = 0; r < 16; ++r) { \
            xa1 = fmaf(re1[r], p1r[r], xa1); xa1 = fmaf(im1[r], p1i[r], xa1); \
            ya1 = fmaf(re1[r], p1i[r], ya1); ya1 = fmaf(-im1[r], p1r[r], ya1); \
        } \
        const float sg = ((lane >> (5 - w)) & 1) ? -1.f : 1.f; \
        o0 = fmaf(xa0, V[w], o0); o0 = fmaf(sg * ya0, V[10 + w], o0); o0 = fmaf(sg * n2s0, V[20 + w], o0); \
        o1 = fmaf(xa1, V[w], o1); o1 = fmaf(sg * ya1, V[10 + w], o1); o1 = fmaf(sg * n2s1, V[20 + w], o1); }
    MD_LANE(0, 32) MD_LANE(1, 16) MD_LANE(2, 8) MD_LANE(3, 4) MD_LANE(4, 2) MD_LANE(5, 1)
#undef MD_LANE

#define MD_REG(w, MK) { \
        float xa0 = 0.f, ya0 = 0.f, za0 = 0.f, xa1 = 0.f, ya1 = 0.f, za1 = 0.f; \
        _Pragma("unroll") \
        for (int r = 0; r < 16; ++r) { \
            if ((r & MK) == 0) { \
                const int r1 = r | MK; \
                xa0 = fmaf(re0[r], re0[r1], xa0); xa0 = fmaf(im0[r], im0[r1], xa0); \
                ya0 = fmaf(re0[r], im0[r1], ya0); ya0 = fmaf(-im0[r], re0[r1], ya0); \
                za0 += fmaf(re0[r], re0[r], im0[r] * im0[r]) - fmaf(re0[r1], re0[r1], im0[r1] * im0[r1]); \
                xa1 = fmaf(re1[r], re1[r1], xa1); xa1 = fmaf(im1[r], im1[r1], xa1); \
                ya1 = fmaf(re1[r], im1[r1], ya1); ya1 = fmaf(-im1[r], re1[r1], ya1); \
                za1 += fmaf(re1[r], re1[r], im1[r] * im1[r]) - fmaf(re1[r1], re1[r1], im1[r1] * im1[r1]); \
            } } \
        o0 = fmaf(2.f * xa0, V[w], o0); o0 = fmaf(2.f * ya0, V[10 + w], o0); o0 = fmaf(za0, V[20 + w], o0); \
        o1 = fmaf(2.f * xa1, V[w], o1); o1 = fmaf(2.f * ya1, V[10 + w], o1); o1 = fmaf(za1, V[20 + w], o1); }
    MD_REG(6, 8) MD_REG(7, 4) MD_REG(8, 2) MD_REG(9, 1)
#undef MD_REG

    o0out = o0; o1out = o1;
}

// ---------------- branch circuits (r12, verified) ----------------

__device__ void branch_gating(const float* __restrict__ gb,
                              const float* __restrict__ b1,
                              const float* __restrict__ W2, const float* __restrict__ b2,
                              const float* __restrict__ w1p, const float* __restrict__ w2p,
                              const float* __restrict__ Wout, const float* __restrict__ bout,
                              float* __restrict__ vbr, float* __restrict__ ws_c, int lane) {
    const float w1v = w1p[0], w2v = w2p[0];
    float bias = 0.f;
    if (lane < 30) {
        float v = 0.f;
        for (int k = 0; k < 30; ++k) v = fmaf(Wout[k], W2[k * 30 + lane], v);
        vbr[lane] = w2v * v;
        bias = Wout[lane] * (w1v * b1[lane] + w2v * b2[lane]);
    }

    float re[16], im[16];
    init_zero(re, im, lane);
    for (int L = 0; L < 2; ++L) {
        const int g0 = L * 30;
        {
            float c0_, s0_, c1_, s1_;
            __sincosf(0.5f * gb[g0 + 0], &s0_, &c0_);
            __sincosf(0.5f * gb[g0 + 1], &s1_, &c1_);
            g_rx2_01(re, im, c0_, s0_, c1_, s1_, lane);
        }
#define BRX(i) { float s_, c_; __sincosf(0.5f * gb[g0 + i], &s_, &c_); g_rx<i>(re, im, c_, s_, lane); }
        BRX(2) BRX(3) BRX(4) BRX(5) BRX(6) BRX(7) BRX(8) BRX(9)
#undef BRX
#define BCRZ(i) { float s_, c_; __sincosf(0.5f * gb[g0 + 10 + i], &s_, &c_); g_crz<i, i + 1>(re, im, c_, s_, lane); }
        ALLQ9(BCRZ)
#undef BCRZ
        {
            float c0_, s0_, c1_, s1_;
            __sincosf(0.5f * gb[g0 + 19 + 0], &s0_, &c0_);
            __sincosf(0.5f * gb[g0 + 19 + 1], &s1_, &c1_);
            g_ry2_01(re, im, c0_, s0_, c1_, s1_, lane);
        }
#define BRY(i) { float s_, c_; __sincosf(0.5f * gb[g0 + 19 + i], &s_, &c_); g_ry<i>(re, im, c_, s_, lane); }
        BRY(2) BRY(3) BRY(4) BRY(5) BRY(6) BRY(7) BRY(8) BRY(9)
#undef BRY
        { float s_, c_; __sincosf(0.5f * gb[g0 + 29], &s_, &c_); g_crz<9, 0>(re, im, c_, s_, lane); }
    }

    float oacc = meas_fold(re, im, vbr, lane) + bias;
    oacc = wred(oacc, lane);
    if (lane == 0) ws_c[0] = oacc + bout[0];
}

__device__ void branch_skip(const float* __restrict__ sp,
                            const float* __restrict__ W3, const float* __restrict__ b3v,
                            const float* __restrict__ w3p,
                            const float* __restrict__ Wout,
                            float* __restrict__ ws_c, int lane) {
    float vk = 0.f;
    if (lane < 30) {
        const int q = (lane < 10) ? lane : ((lane < 20) ? lane - 10 : lane - 20);
        float c1, s1, c2, s2, c3, s3;
        __sincosf(0.5f * sp[q],      &s1, &c1);
        __sincosf(0.5f * sp[10 + q], &s2, &c2);
        __sincosf(0.5f * sp[20 + q], &s3, &c3);
        float a2r = c2 * c1, a2i = s2 * s1, b2r = s2 * c1, b2i = -c2 * s1;
        float a3r = fmaf(a2i,  s3, a2r * c3), a3i = fmaf(-a2r, s3, a2i * c3);
        float b3r = fmaf(-b2i, s3, b2r * c3), b3i = fmaf( b2r, s3, b2i * c3);
        float m;
        if (lane < 10)      m = 2.f * (a3r * b3r + a3i * b3i);
        else if (lane < 20) m = 2.f * (a3r * b3i - a3i * b3r);
        else                m = (a3r * a3r + a3i * a3i) - (b3r * b3r + b3i * b3i);
        float v = 0.f;
        for (int k = 0; k < 30; ++k) v = fmaf(Wout[k], W3[k * 30 + lane], v);
        vk = w3p[0] * fmaf(m, v, Wout[lane] * b3v[lane]);
    }
    vk = wred(vk, lane);
    if (lane == 0) ws_c[0] = vk;
}

// ---------------- main kernel ----------------
// grid = B/8 main blocks (4 waves x 2 elements) + 1 branch block.

__global__ void __launch_bounds__(TPB, 1) k_main(
    const float* __restrict__ x, const float* __restrict__ Wp,
    const float* __restrict__ bp_, const float* __restrict__ qb,
    const float* __restrict__ bpar, const float* __restrict__ cpar, const float* __restrict__ dtpar,
    const float* __restrict__ gb, const float* __restrict__ sp,
    const float* __restrict__ W1, const float* __restrict__ b1,
    const float* __restrict__ W2, const float* __restrict__ b2,
    const float* __restrict__ W3, const float* __restrict__ b3,
    const float* __restrict__ w1p, const float* __restrict__ w2p, const float* __restrict__ w3p,
    const float* __restrict__ Wout, const float* __restrict__ bout,
    float* __restrict__ ws, int B) {

    const int wv = threadIdx.x >> 6, lane = threadIdx.x & 63;

    __shared__ float vbr[32];

    if (blockIdx.x == gridDim.x - 1) {
        if (wv == 0) branch_gating(gb, b1, W2, b2, w1p, w2p, Wout, bout, vbr, ws + B, lane);
        else if (wv == 1) branch_skip(sp, W3, b3, w3p, Wout, ws + B + 1, lane);
        return;
    }

    const int b0 = blockIdx.x * 8 + wv * 2;
    const int b1i = b0 + 1;
    const int bb0 = (b0 < B) ? b0 : (B - 1);
    const int bb1 = (b1i < B) ? b1i : (B - 1);

    __shared__ float proj[4][2][80];
    __shared__ float ac1[4][2][10], as1[4][2][10], ac2[4][2][10], as2[4][2][10];
    __shared__ float gc[4][2][60], gs[4][2][60];
    __shared__ float ub[4][2][80];
    __shared__ float uraw[4][32], uu[4][32];

    // ---- projection: Wp rows loaded ONCE, dotted with both x rows ----
    const int sub = lane & 15, grp = lane >> 4;
    float4 xv0[4], xv1[4];
    {
        const float* xr0 = x + (size_t)bb0 * 256 + sub * 16;
        const float* xr1 = x + (size_t)bb1 * 256 + sub * 16;
#pragma unroll
        for (int j = 0; j < 4; ++j) xv0[j] = reinterpret_cast<const float4*>(xr0)[j];
#pragma unroll
        for (int j = 0; j < 4; ++j) xv1[j] = reinterpret_cast<const float4*>(xr1)[j];
    }
#pragma unroll 4
    for (int p = 0; p < 20; ++p) {
        const int row = p * 4 + grp;
        const float* wr = Wp + (size_t)row * 256 + sub * 16;
        float a0 = 0.f, a1 = 0.f;
#pragma unroll
        for (int j = 0; j < 4; ++j) {
            float4 w4 = reinterpret_cast<const float4*>(wr)[j];
            a0 = fmaf(xv0[j].x, w4.x, a0); a0 = fmaf(xv0[j].y, w4.y, a0);
            a0 = fmaf(xv0[j].z, w4.z, a0); a0 = fmaf(xv0[j].w, w4.w, a0);
            a1 = fmaf(xv1[j].x, w4.x, a1); a1 = fmaf(xv1[j].y, w4.y, a1);
            a1 = fmaf(xv1[j].z, w4.z, a1); a1 = fmaf(xv1[j].w, w4.w, a1);
        }
        a0 += lx<1>(a0, lane); a1 += lx<1>(a1, lane);
        a0 += lx<2>(a0, lane); a1 += lx<2>(a1, lane);
        a0 += lx<4>(a0, lane); a1 += lx<4>(a1, lane);
        a0 += lx<8>(a0, lane); a1 += lx<8>(a1, lane);
        if (sub == 0) { proj[wv][0][row] = a0; proj[wv][1][row] = a1; }
    }

    // ---- angle prep (both elements) ----
    {
#define DO_ANGLE(E, IDX) { \
        const int idx = (IDX); \
        float ang = TWO_PI_F / (1.f + __expf(-(proj[wv][E][idx] + bp_[idx]))) + qb[idx]; \
        const int l = (idx >= 40) ? 1 : 0; \
        const int p = idx - 40 * l; \
        float s_, c_; \
        if (p < 10) { \
            __sincosf(0.5f * ang, &s_, &c_); \
            if (l == 0) { ac1[wv][E][p] = c_; as1[wv][E][p] = s_; } \
            else        { ac2[wv][E][p] = c_; as2[wv][E][p] = s_; } \
        } else if (p < 20) { \
            __sincosf(0.5f * ang, &s_, &c_); \
            gc[wv][E][l * 30 + p - 10] = c_; gs[wv][E][l * 30 + p - 10] = s_; \
        } else if (p < 30) { \
            __sincosf(0.5f * (ang + bpar[p - 20]), &s_, &c_); \
            gc[wv][E][l * 30 + 10 + p - 20] = c_; gs[wv][E][l * 30 + 10 + p - 20] = s_; \
        } else { \
            __sincosf(0.5f * ang, &s_, &c_); \
            gc[wv][E][l * 30 + 20 + p - 30] = c_; gs[wv][E][l * 30 + 20 + p - 30] = s_; \
        } }
        DO_ANGLE(0, lane)
        DO_ANGLE(1, lane)
        if (lane < 16) { DO_ANGLE(0, 64 + lane) DO_ANGLE(1, 64 + lane) }
#undef DO_ANGLE

        // parameter-only fold vector (shared by both elements)
        if (lane < 30) {
            float ut = 0.f;
            for (int k = 0; k < 30; ++k) ut = fmaf(Wout[k], W1[k * 30 + lane], ut);
            uraw[wv][lane] = w1p[0] * ut;
        }
        if (lane < 10) {
            float cg, sgf, cd, sdf;
            __sincosf(cpar[lane],  &sgf, &cg);
            __sincosf(dtpar[lane], &sdf, &cd);
            float uX = uraw[wv][lane], uY = uraw[wv][10 + lane], uZ = uraw[wv][20 + lane];
            uu[wv][lane]      =  uX * cg + uY * cd * sgf + uZ * sdf * sgf;
            uu[wv][10 + lane] = -uX * sgf + uY * cd * cg + uZ * sdf * cg;
            uu[wv][20 + lane] = -uY * sdf + uZ * cd;
        }
        // per-element boundary U: lanes 0-9 -> elem0, lanes 32-41 -> elem1
        const int eSel = (lane >= 32) ? 1 : 0;
        const int ql = lane - 32 * eSel;
        if (ql < 10) {
            float ca = ac2[wv][eSel][ql], sa = as2[wv][eSel][ql];
            float cg2, sg2, cd2, sd2;
            __sincosf(0.5f * cpar[ql],  &sg2, &cg2);
            __sincosf(0.5f * dtpar[ql], &sd2, &cd2);
            float A = ca * cd2, Bv = sa * sd2;
            float C = -sa * cd2, D = -ca * sd2;
            float E = sa * cd2,  F = -ca * sd2;
            float G = ca * cd2,  H = -sa * sd2;
            float* U = &ub[wv][eSel][ql * 8];
            U[0] = cg2 * A + sg2 * Bv;  U[1] = cg2 * Bv - sg2 * A;
            U[2] = cg2 * C - sg2 * D;   U[3] = sg2 * C + cg2 * D;
            U[4] = cg2 * E + sg2 * F;   U[5] = cg2 * F - sg2 * E;
            U[6] = cg2 * G - sg2 * H;   U[7] = sg2 * G + cg2 * H;
        }
    }

    // ---- product initial states ----
    float re0[16], im0[16], re1[16], im1[16];
    {
        const float* AC = ac1[wv][0]; const float* AS = as1[wv][0];
        float pl = ((lane >> 5) & 1) ? AS[0] : AC[0];
        pl *= ((lane >> 4) & 1) ? AS[1] : AC[1];
        pl *= ((lane >> 3) & 1) ? AS[2] : AC[2];
        pl *= ((lane >> 2) & 1) ? AS[3] : AC[3];
        pl *= ((lane >> 1) & 1) ? AS[4] : AC[4];
        pl *= ( lane       & 1) ? AS[5] : AC[5];
#pragma unroll
        for (int r = 0; r < 16; ++r) {
            float p = ((r >> 3) & 1) ? AS[6] : AC[6];
            p *= ((r >> 2) & 1) ? AS[7] : AC[7];
            p *= ((r >> 1) & 1) ? AS[8] : AC[8];
            p *= ( r       & 1) ? AS[9] : AC[9];
            re0[r] = pl * p; im0[r] = 0.f;
        }
    }
    {
        const float* AC = ac1[wv][1]; const float* AS = as1[wv][1];
        float pl = ((lane >> 5) & 1) ? AS[0] : AC[0];
        pl *= ((lane >> 4) & 1) ? AS[1] : AC[1];
        pl *= ((lane >> 3) & 1) ? AS[2] : AC[2];
        pl *= ((lane >> 2) & 1) ? AS[3] : AC[3];
        pl *= ((lane >> 1) & 1) ? AS[4] : AC[4];
        pl *= ( lane       & 1) ? AS[5] : AC[5];
#pragma unroll
        for (int r = 0; r < 16; ++r) {
            float p = ((r >> 3) & 1) ? AS[6] : AC[6];
            p *= ((r >> 2) & 1) ? AS[7] : AC[7];
            p *= ((r >> 1) & 1) ? AS[8] : AC[8];
            p *= ( r       & 1) ? AS[9] : AC[9];
            re1[r] = pl * p; im1[r] = 0.f;
        }
    }

    // ---- fused circuit (duo) ----
    const float* GC0 = gc[wv][0]; const float* GS0 = gs[wv][0];
    const float* GC1 = gc[wv][1]; const float* GS1 = gs[wv][1];

#define RING_D(base, YYf) \
    g_xy_d<0, 1, YYf>(re0, im0, re1, im1, GC0[(base)+0], GS0[(base)+0], GC1[(base)+0], GS1[(base)+0], lane); \
    g_xy_d<1, 2, YYf>(re0, im0, re1, im1, GC0[(base)+1], GS0[(base)+1], GC1[(base)+1], GS1[(base)+1], lane); \
    g_xy_d<2, 3, YYf>(re0, im0, re1, im1, GC0[(base)+2], GS0[(base)+2], GC1[(base)+2], GS1[(base)+2], lane); \
    g_xy_d<3, 4, YYf>(re0, im0, re1, im1, GC0[(base)+3], GS0[(base)+3], GC1[(base)+3], GS1[(base)+3], lane); \
    g_xy_d<4, 5, YYf>(re0, im0, re1, im1, GC0[(base)+4], GS0[(base)+4], GC1[(base)+4], GS1[(base)+4], lane); \
    g_xy_d<5, 6, YYf>(re0, im0, re1, im1, GC0[(base)+5], GS0[(base)+5], GC1[(base)+5], GS1[(base)+5], lane); \
    g_xy_d<6, 7, YYf>(re0, im0, re1, im1, GC0[(base)+6], GS0[(base)+6], GC1[(base)+6], GS1[(base)+6], lane); \
    g_xy_d<7, 8, YYf>(re0, im0, re1, im1, GC0[(base)+7], GS0[(base)+7], GC1[(base)+7], GS1[(base)+7], lane); \
    g_xy_d<8, 9, YYf>(re0, im0, re1, im1, GC0[(base)+8], GS0[(base)+8], GC1[(base)+8], GS1[(base)+8], lane); \
    g_xy_d<9, 0, YYf>(re0, im0, re1, im1, GC0[(base)+9], GS0[(base)+9], GC1[(base)+9], GS1[(base)+9], lane);

#define CD_D(base) \
    g_ry_d<0>(re0, im0, re1, im1, GC0[(base)+0], GS0[(base)+0], GC1[(base)+0], GS1[(base)+0], lane); \
    g_ry_d<1>(re0, im0, re1, im1, GC0[(base)+1], GS0[(base)+1], GC1[(base)+1], GS1[(base)+1], lane); \
    g_ry_d<2>(re0, im0, re1, im1, GC0[(base)+2], GS0[(base)+2], GC1[(base)+2], GS1[(base)+2], lane); \
    g_ry_d<3>(re0, im0, re1, im1, GC0[(base)+3], GS0[(base)+3], GC1[(base)+3], GS1[(base)+3], lane); \
    g_ry_d<4>(re0, im0, re1, im1, GC0[(base)+4], GS0[(base)+4], GC1[(base)+4], GS1[(base)+4], lane); \
    g_ry_d<5>(re0, im0, re1, im1, GC0[(base)+5], GS0[(base)+5], GC1[(base)+5], GS1[(base)+5], lane); \
    g_ry_d<6>(re0, im0, re1, im1, GC0[(base)+6], GS0[(base)+6], GC1[(base)+6], GS1[(base)+6], lane); \
    g_ry_d<7>(re0, im0, re1, im1, GC0[(base)+7], GS0[(base)+7], GC1[(base)+7], GS1[(base)+7], lane); \
    g_ry_d<8>(re0, im0, re1, im1, GC0[(base)+8], GS0[(base)+8], GC1[(base)+8], GS1[(base)+8], lane); \
    g_ry_d<9>(re0, im0, re1, im1, GC0[(base)+9], GS0[(base)+9], GC1[(base)+9], GS1[(base)+9], lane);

    RING_D(0, false)
    CD_D(10)
    RING_D(20, true)
#define UB_D(i) g_u1_d<i>(re0, im0, re1, im1, &ub[wv][0][(i) * 8], &ub[wv][1][(i) * 8], lane);
    ALLQ(UB_D)
#undef UB_D
    RING_D(30, false)
    CD_D(40)
    RING_D(50, true)
#undef RING_D
#undef CD_D

    // ---- duo folded measurement ----
    float o0, o1;
    meas_fold_d(re0, im0, re1, im1, uu[wv], lane, o0, o1);
    o0 = wred(o0, lane);
    o1 = wred(o1, lane);
    if (lane == 0) {
        if (b0 < B) ws[b0] = o0;
        if (b1i < B) ws[b1i] = o1;
    }
}

__global__ void k_out(const float* __restrict__ ws, float* __restrict__ out, int B) {
    int i = blockIdx.x * blockDim.x + threadIdx.x;
    if (i < B) out[i] = ws[i] + ws[B] + ws[B + 1];
}

extern "C" void kernel_launch(void* const* d_in, const int* in_sizes, int n_in,
                              void* d_out, int out_size, void* d_ws, size_t ws_size,
                              hipStream_t stream) {
    const float* x         = (const float*)d_in[0];
    const float* W_proj    = (const float*)d_in[1];
    const float* b_proj    = (const float*)d_in[2];
    const float* qlcu_base = (const float*)d_in[3];
    const float* gate_base = (const float*)d_in[4];
    const float* skip_base = (const float*)d_in[5];
    const float* b_params  = (const float*)d_in[6];
    const float* c_params  = (const float*)d_in[7];
    const float* dt_params = (const float*)d_in[8];
    const float* W1    = (const float*)d_in[9];
    const float* b1    = (const float*)d_in[10];
    const float* W2    = (const float*)d_in[11];
    const float* b2    = (const float*)d_in[12];
    const float* W3    = (const float*)d_in[13];
    const float* b3    = (const float*)d_in[14];
    const float* w1    = (const float*)d_in[15];
    const float* w2    = (const float*)d_in[16];
    const float* w3    = (const float*)d_in[17];
    const float* W_out = (const float*)d_in[18];
    const float* b_out = (const float*)d_in[19];
    float* out = (float*)d_out;
    float* ws  = (float*)d_ws;

    const int B = in_sizes[0] / 256;   // FEATURE_DIM = 256
    const int nb = (B + 7) / 8;        // 256 for B=2048 (exact)

    hipLaunchKernelGGL(k_main, dim3(nb + 1), dim3(TPB), 0, stream,
                       x, W_proj, b_proj, qlcu_base, b_params, c_params, dt_params,
                       gate_base, skip_base, W1, b1, W2, b2, W3, b3, w1, w2, w3,
                       W_out, b_out, ws, B);
    hipLaunchKernelGGL(k_out, dim3((B + 255) / 256), dim3(256), 0, stream, ws, out, B);
}

// Round 15
// 55.874 us; speedup vs baseline: 1.0039x; 1.0039x over previous
//
#include <hip/hip_runtime.h>
#include <math.h>

#define TPB 320
#define TWO_PI_F 6.283185307179586f

// State layout: one wave (64 lanes) holds 1024 amplitudes.
// s = (lane << 4) | r,  r = 0..15 in registers re[16], im[16].
// Qubit w -> state bit (9-w).  w <= 5: lane bit (5-w).  w >= 6: local bit (9-w).
// Stagger: layers are commuting sets; even/odd waves order each layer
// differently (DS-heavy fused pair first vs last) to desynchronize DS bursts.

#define ALLQ(OP) OP(0) OP(1) OP(2) OP(3) OP(4) OP(5) OP(6) OP(7) OP(8) OP(9)
#define ALLQ9(OP) OP(0) OP(1) OP(2) OP(3) OP(4) OP(5) OP(6) OP(7) OP(8)

template<int CTRL>
__device__ __forceinline__ float dppmv(float v) {
    return __builtin_bit_cast(float,
        __builtin_amdgcn_update_dpp(0, __builtin_bit_cast(int, v), CTRL, 0xF, 0xF, true));
}

template<int LM>
__device__ __forceinline__ float lx(float v, int lane) {
    (void)lane;
    if constexpr (LM == 1)       return dppmv<0xB1>(v);
    else if constexpr (LM == 2)  return dppmv<0x4E>(v);
    else if constexpr (LM == 3)  return dppmv<0x1B>(v);
    else if constexpr (LM == 4)  return dppmv<0x1B>(dppmv<0x141>(v));   // 7^3
    else if constexpr (LM == 6)  return dppmv<0xB1>(dppmv<0x141>(v));   // 7^1
    else if constexpr (LM == 8)  return dppmv<0x128>(v);                // ror 8
    else if constexpr (LM == 12) return dppmv<0x1B>(dppmv<0x140>(v));   // 15^3
    else                         return __shfl_xor(v, LM);              // 16,24,32,48,56
}

template<int W>
__device__ __forceinline__ int qbit(int lane, int r) {
    if constexpr (W <= 5) return (lane >> (5 - W)) & 1;
    else                  return (r >> (9 - W)) & 1;
}

// ---------------- single gates (prefetch-then-compute) ----------------

template<int W>
__device__ __forceinline__ void g_ry(float (&re)[16], float (&im)[16], float c, float s, int lane) {
    if constexpr (W <= 5) {
        constexpr int LM = 1 << (5 - W);
        const float ss = ((lane >> (5 - W)) & 1) ? s : -s;
        float pr[16], pi[16];
#pragma unroll
        for (int r = 0; r < 16; ++r) { pr[r] = lx<LM>(re[r], lane); pi[r] = lx<LM>(im[r], lane); }
#pragma unroll
        for (int r = 0; r < 16; ++r) {
            re[r] = fmaf(ss, pr[r], c * re[r]);
            im[r] = fmaf(ss, pi[r], c * im[r]);
        }
    } else {
        constexpr int MK = 1 << (9 - W);
#pragma unroll
        for (int r = 0; r < 16; ++r) {
            if ((r & MK) == 0) {
                const int r1 = r | MK;
                float r0 = re[r], i0 = im[r], r1v = re[r1], i1 = im[r1];
                re[r]  = fmaf(-s, r1v, c * r0);
                im[r]  = fmaf(-s, i1,  c * i0);
                re[r1] = fmaf( s, r0,  c * r1v);
                im[r1] = fmaf( s, i0,  c * i1);
            }
        }
    }
}

template<int W>
__device__ __forceinline__ void g_rx(float (&re)[16], float (&im)[16], float c, float s, int lane) {
    if constexpr (W <= 5) {
        constexpr int LM = 1 << (5 - W);
        float pr[16], pi[16];
#pragma unroll
        for (int r = 0; r < 16; ++r) { pr[r] = lx<LM>(re[r], lane); pi[r] = lx<LM>(im[r], lane); }
#pragma unroll
        for (int r = 0; r < 16; ++r) {
            re[r] = fmaf( s, pi[r], c * re[r]);
            im[r] = fmaf(-s, pr[r], c * im[r]);
        }
    } else {
        constexpr int MK = 1 << (9 - W);
#pragma unroll
        for (int r = 0; r < 16; ++r) {
            if ((r & MK) == 0) {
                const int r1 = r | MK;
                float r0 = re[r], i0 = im[r], r1v = re[r1], i1 = im[r1];
                re[r]  = fmaf( s, i1,  c * r0);
                im[r]  = fmaf(-s, r1v, c * i0);
                re[r1] = fmaf( s, i0,  c * r1v);
                im[r1] = fmaf(-s, r0,  c * i1);
            }
        }
    }
}

template<int C, int T>
__device__ __forceinline__ void g_crz(float (&re)[16], float (&im)[16], float c, float s, int lane) {
#pragma unroll
    for (int r = 0; r < 16; ++r) {
        const int cb = qbit<C>(lane, r);
        const int tb = qbit<T>(lane, r);
        const float cc  = cb ? c : 1.f;
        const float sp2 = cb ? (tb ? s : -s) : 0.f;
        float rr = re[r], ii = im[r];
        re[r] = cc * rr - sp2 * ii;
        im[r] = cc * ii + sp2 * rr;
    }
}

template<int A, int Bq, bool YY>
__device__ __forceinline__ void g_xy(float (&re)[16], float (&im)[16], float c, float s, int lane) {
    constexpr int bpA = 9 - A, bpB = 9 - Bq;
    constexpr int LM   = ((bpA >= 4) ? (1 << (bpA - 4)) : 0) | ((bpB >= 4) ? (1 << (bpB - 4)) : 0);
    constexpr int LOCM = ((bpA < 4) ? (1 << bpA) : 0) | ((bpB < 4) ? (1 << bpB) : 0);
    float pr[16], pi[16];
#pragma unroll
    for (int r = 0; r < 16; ++r) {
        float vr = re[r ^ LOCM], vi = im[r ^ LOCM];
        if constexpr (LM != 0) { pr[r] = lx<LM>(vr, lane); pi[r] = lx<LM>(vi, lane); }
        else                   { pr[r] = vr; pi[r] = vi; }
    }
#pragma unroll
    for (int r = 0; r < 16; ++r) {
        float sg;
        if constexpr (YY) {
            const int bA = qbit<A>(lane, r);
            const int bB = qbit<Bq>(lane, r);
            sg = (bA == bB) ? -s : s;
        } else sg = s;
        float rr = re[r], ii = im[r];
        re[r] = fmaf( sg, pi[r], c * rr);
        im[r] = fmaf(-sg, pr[r], c * ii);
    }
}

// general 1-qubit gate U = [[u00,u01],[u10,u11]] complex, entries in U[0..7]
template<int W>
__device__ __forceinline__ void g_u1(float (&re)[16], float (&im)[16], const float* U, int lane) {
    const float u00r=U[0], u00i=U[1], u01r=U[2], u01i=U[3];
    const float u10r=U[4], u10i=U[5], u11r=U[6], u11i=U[7];
    if constexpr (W <= 5) {
        constexpr int LM = 1 << (5 - W);
        const int side = (lane >> (5 - W)) & 1;
        const float aR = side ? u11r : u00r, aI = side ? u11i : u00i;
        const float bR = side ? u10r : u01r, bI = side ? u10i : u01i;
        float pr[16], pi[16];
#pragma unroll
        for (int r = 0; r < 16; ++r) { pr[r] = lx<LM>(re[r], lane); pi[r] = lx<LM>(im[r], lane); }
#pragma unroll
        for (int r = 0; r < 16; ++r) {
            float rr = re[r], ii = im[r];
            float nr = aR * rr; nr = fmaf(-aI, ii, nr); nr = fmaf(bR, pr[r], nr); nr = fmaf(-bI, pi[r], nr);
            float ni = aR * ii; ni = fmaf( aI, rr, ni); ni = fmaf(bR, pi[r], ni); ni = fmaf( bI, pr[r], ni);
            re[r] = nr; im[r] = ni;
        }
    } else {
        constexpr int MK = 1 << (9 - W);
#pragma unroll
        for (int r = 0; r < 16; ++r) {
            if ((r & MK) == 0) {
                const int r1 = r | MK;
                float r0 = re[r], i0 = im[r], r1v = re[r1], i1 = im[r1];
                float a = u00r*r0; a = fmaf(-u00i, i0, a); a = fmaf(u01r, r1v, a); a = fmaf(-u01i, i1, a);
                float b = u00r*i0; b = fmaf( u00i, r0, b); b = fmaf(u01r, i1,  b); b = fmaf( u01i, r1v, b);
                float c = u10r*r0; c = fmaf(-u10i, i0, c); c = fmaf(u11r, r1v, c); c = fmaf(-u11i, i1, c);
                float d = u10r*i0; d = fmaf( u10i, r0, d); d = fmaf(u11r, i1,  d); d = fmaf( u11i, r1v, d);
                re[r] = a; im[r] = b; re[r1] = c; im[r1] = d;
            }
        }
    }
}

// ---------------- fused pair gates ----------------

__device__ __forceinline__ void g_ry2_01(float (&re)[16], float (&im)[16],
                                         float c0, float s0, float c1, float s1, int lane) {
    float ar[16], ai[16], br[16], bi[16], cr2[16], ci2[16];
#pragma unroll
    for (int r = 0; r < 16; ++r) { ar[r] = lx<32>(re[r], lane); ai[r] = lx<32>(im[r], lane); }
#pragma unroll
    for (int r = 0; r < 16; ++r) { br[r] = lx<16>(re[r], lane); bi[r] = lx<16>(im[r], lane); }
#pragma unroll
    for (int r = 0; r < 16; ++r) { cr2[r] = lx<48>(re[r], lane); ci2[r] = lx<48>(im[r], lane); }
    const float sg0 = ((lane >> 5) & 1) ? s0 : -s0;
    const float sg1 = ((lane >> 4) & 1) ? s1 : -s1;
    const float k0 = c0 * c1, k1 = c1 * sg0, k2 = c0 * sg1, k3 = sg0 * sg1;
#pragma unroll
    for (int r = 0; r < 16; ++r) {
        float o_r = k0 * re[r];
        o_r = fmaf(k1, ar[r], o_r); o_r = fmaf(k2, br[r], o_r); o_r = fmaf(k3, cr2[r], o_r);
        float o_i = k0 * im[r];
        o_i = fmaf(k1, ai[r], o_i); o_i = fmaf(k2, bi[r], o_i); o_i = fmaf(k3, ci2[r], o_i);
        re[r] = o_r; im[r] = o_i;
    }
}

__device__ __forceinline__ void g_rx2_01(float (&re)[16], float (&im)[16],
                                         float c0, float s0, float c1, float s1, int lane) {
    float ar[16], ai[16], br[16], bi[16], cr2[16], ci2[16];
#pragma unroll
    for (int r = 0; r < 16; ++r) { ar[r] = lx<32>(re[r], lane); ai[r] = lx<32>(im[r], lane); }
#pragma unroll
    for (int r = 0; r < 16; ++r) { br[r] = lx<16>(re[r], lane); bi[r] = lx<16>(im[r], lane); }
#pragma unroll
    for (int r = 0; r < 16; ++r) { cr2[r] = lx<48>(re[r], lane); ci2[r] = lx<48>(im[r], lane); }
    const float k0 = c0 * c1, kA = c1 * s0, kB = c0 * s1, kC = s0 * s1;
#pragma unroll
    for (int r = 0; r < 16; ++r) {
        float rr = re[r], ii = im[r];
        float o_r = k0 * rr;
        o_r = fmaf(kA, ai[r], o_r); o_r = fmaf(kB, bi[r], o_r); o_r = fmaf(-kC, cr2[r], o_r);
        float o_i = k0 * ii;
        o_i = fmaf(-kA, ar[r], o_i); o_i = fmaf(-kB, br[r], o_i); o_i = fmaf(-kC, ci2[r], o_i);
        re[r] = o_r; im[r] = o_i;
    }
}

__device__ __forceinline__ void g_u2_01(float (&re)[16], float (&im)[16],
                                        const float* U0, const float* U1, int lane) {
    const int b0 = (lane >> 5) & 1, b1 = (lane >> 4) & 1;
    const float u0o_r = U0[(b0*2+b0)*2],       u0o_i = U0[(b0*2+b0)*2+1];
    const float u0f_r = U0[(b0*2+(b0^1))*2],   u0f_i = U0[(b0*2+(b0^1))*2+1];
    const float u1o_r = U1[(b1*2+b1)*2],       u1o_i = U1[(b1*2+b1)*2+1];
    const float u1f_r = U1[(b1*2+(b1^1))*2],   u1f_i = U1[(b1*2+(b1^1))*2+1];
    const float K00r = u0o_r*u1o_r - u0o_i*u1o_i, K00i = u0o_r*u1o_i + u0o_i*u1o_r;
    const float K01r = u0o_r*u1f_r - u0o_i*u1f_i, K01i = u0o_r*u1f_i + u0o_i*u1f_r;
    const float K10r = u0f_r*u1o_r - u0f_i*u1o_i, K10i = u0f_r*u1o_i + u0f_i*u1o_r;
    const float K11r = u0f_r*u1f_r - u0f_i*u1f_i, K11i = u0f_r*u1f_i + u0f_i*u1f_r;
    float ar[16], ai[16], br[16], bi[16], cr2[16], ci2[16];
#pragma unroll
    for (int r = 0; r < 16; ++r) { ar[r] = lx<32>(re[r], lane); ai[r] = lx<32>(im[r], lane); }
#pragma unroll
    for (int r = 0; r < 16; ++r) { br[r] = lx<16>(re[r], lane); bi[r] = lx<16>(im[r], lane); }
#pragma unroll
    for (int r = 0; r < 16; ++r) { cr2[r] = lx<48>(re[r], lane); ci2[r] = lx<48>(im[r], lane); }
#pragma unroll
    for (int r = 0; r < 16; ++r) {
        float rr = re[r], ii = im[r];
        float o_r = K00r * rr;         o_r = fmaf(-K00i, ii, o_r);
        o_r = fmaf(K01r, br[r], o_r);  o_r = fmaf(-K01i, bi[r], o_r);
        o_r = fmaf(K10r, ar[r], o_r);  o_r = fmaf(-K10i, ai[r], o_r);
        o_r = fmaf(K11r, cr2[r], o_r); o_r = fmaf(-K11i, ci2[r], o_r);
        float o_i = K00r * ii;         o_i = fmaf(K00i, rr, o_i);
        o_i = fmaf(K01r, bi[r], o_i);  o_i = fmaf(K01i, br[r], o_i);
        o_i = fmaf(K10r, ai[r], o_i);  o_i = fmaf(K10i, ar[r], o_i);
        o_i = fmaf(K11r, ci2[r], o_i); o_i = fmaf(K11i, cr2[r], o_i);
        re[r] = o_r; im[r] = o_i;
    }
}

// fused ring pair: gate a = XY(1,2) [LM 24], gate b = XY(9,0) [LM 32, LOCM 1].
__device__ __forceinline__ void g_ring2(float (&re)[16], float (&im)[16],
                                        float ca, float sa, float cb, float sb,
                                        bool yy, int lane) {
    float ar[16], ai[16], br[16], bi[16], cr2[16], ci2[16];
#pragma unroll
    for (int r = 0; r < 16; ++r) { ar[r] = lx<24>(re[r], lane); ai[r] = lx<24>(im[r], lane); }
#pragma unroll
    for (int r = 0; r < 16; ++r) { br[r] = lx<32>(re[r ^ 1], lane); bi[r] = lx<32>(im[r ^ 1], lane); }
#pragma unroll
    for (int r = 0; r < 16; ++r) { cr2[r] = lx<56>(re[r ^ 1], lane); ci2[r] = lx<56>(im[r ^ 1], lane); }
    float ka, kb0, kb1, kab0, kab1;
    if (yy) {
        const bool ea = (((lane >> 4) & 1) == ((lane >> 3) & 1));
        const float sga = ea ? -sa : sa;
        const int b0l = (lane >> 5) & 1;
        const float sgb0 = (0 == b0l) ? -sb : sb;
        const float sgb1 = (1 == b0l) ? -sb : sb;
        ka = cb * sga; kb0 = ca * sgb0; kb1 = ca * sgb1;
        kab0 = sga * sgb0; kab1 = sga * sgb1;
    } else {
        ka = cb * sa; kb0 = kb1 = ca * sb; kab0 = kab1 = sa * sb;
    }
    const float k0 = ca * cb;
#pragma unroll
    for (int r = 0; r < 16; ++r) {
        const float kb  = (r & 1) ? kb1  : kb0;
        const float kab = (r & 1) ? kab1 : kab0;
        float rr = re[r], ii = im[r];
        float o_r = k0 * rr;
        o_r = fmaf(ka, ai[r], o_r); o_r = fmaf(kb, bi[r], o_r); o_r = fmaf(-kab, cr2[r], o_r);
        float o_i = k0 * ii;
        o_i = fmaf(-ka, ar[r], o_i); o_i = fmaf(-kb, br[r], o_i); o_i = fmaf(-kab, ci2[r], o_i);
        re[r] = o_r; im[r] = o_i;
    }
}

// full-wave reduce (sum)
__device__ __forceinline__ float wred(float v, int lane) {
    v += lx<1>(v, lane); v += lx<2>(v, lane); v += lx<4>(v, lane);
    v += lx<8>(v, lane); v += lx<16>(v, lane); v += lx<32>(v, lane);
    return v;
}

// ---------------- folded measurement (shared by main + gating) ----------------
__device__ float meas_fold(const float (&re)[16], const float (&im)[16],
                           const float* __restrict__ V, int lane) {
    float oacc = 0.f;
    float q0r[16], q0i[16], q1r[16], q1i[16];
#pragma unroll
    for (int r = 0; r < 16; ++r) { q0r[r] = lx<32>(re[r], lane); q0i[r] = lx<32>(im[r], lane); }
#pragma unroll
    for (int r = 0; r < 16; ++r) { q1r[r] = lx<16>(re[r], lane); q1i[r] = lx<16>(im[r], lane); }

    float n2[16], n2s = 0.f;
#pragma unroll
    for (int r = 0; r < 16; ++r) { n2[r] = fmaf(re[r], re[r], im[r] * im[r]); n2s += n2[r]; }

#define M_LANE(w, LM_) { \
        float pr[16], pi[16]; \
        _Pragma("unroll") \
        for (int r = 0; r < 16; ++r) { pr[r] = lx<LM_>(re[r], lane); pi[r] = lx<LM_>(im[r], lane); } \
        float xa = 0.f, ya = 0.f; \
        _Pragma("unroll") \
        for (int r = 0; r < 16; ++r) { \
            xa = fmaf(re[r], pr[r], xa); xa = fmaf(im[r], pi[r], xa); \
            ya = fmaf(re[r], pi[r], ya); ya = fmaf(-im[r], pr[r], ya); \
        } \
        const float sg = ((lane >> (5 - w)) & 1) ? -1.f : 1.f; \
        oacc = fmaf(xa, V[w], oacc); \
        oacc = fmaf(sg * ya, V[10 + w], oacc); \
        oacc = fmaf(sg * n2s, V[20 + w], oacc); }
    M_LANE(2, 8) M_LANE(3, 4) M_LANE(4, 2) M_LANE(5, 1)
#undef M_LANE

#define M_REG(w, MK) { \
        float xa = 0.f, ya = 0.f, za = 0.f; \
        _Pragma("unroll") \
        for (int r = 0; r < 16; ++r) { \
            if ((r & MK) == 0) { \
                const int r1 = r | MK; \
                xa = fmaf(re[r], re[r1], xa); xa = fmaf(im[r], im[r1], xa); \
                ya = fmaf(re[r], im[r1], ya); ya = fmaf(-im[r], re[r1], ya); \
                za += n2[r] - n2[r1]; \
            } } \
        oacc = fmaf(2.f * xa, V[w], oacc); \
        oacc = fmaf(2.f * ya, V[10 + w], oacc); \
        oacc = fmaf(za, V[20 + w], oacc); }
    M_REG(6, 8) M_REG(7, 4) M_REG(8, 2) M_REG(9, 1)
#undef M_REG

    {
        float xa = 0.f, ya = 0.f;
#pragma unroll
        for (int r = 0; r < 16; ++r) {
            xa = fmaf(re[r], q0r[r], xa); xa = fmaf(im[r], q0i[r], xa);
            ya = fmaf(re[r], q0i[r], ya); ya = fmaf(-im[r], q0r[r], ya);
        }
        const float sg = ((lane >> 5) & 1) ? -1.f : 1.f;
        oacc = fmaf(xa, V[0], oacc);
        oacc = fmaf(sg * ya, V[10], oacc);
        oacc = fmaf(sg * n2s, V[20], oacc);
    }
    {
        float xa = 0.f, ya = 0.f;
#pragma unroll
        for (int r = 0; r < 16; ++r) {
            xa = fmaf(re[r], q1r[r], xa); xa = fmaf(im[r], q1i[r], xa);
            ya = fmaf(re[r], q1i[r], ya); ya = fmaf(-im[r], q1r[r], ya);
        }
        const float sg = ((lane >> 4) & 1) ? -1.f : 1.f;
        oacc = fmaf(xa, V[1], oacc);
        oacc = fmaf(sg * ya, V[11], oacc);
        oacc = fmaf(sg * n2s, V[21], oacc);
    }
    return oacc;
}

__device__ __forceinline__ void init_state(float (&re)[16], float (&im)[16], int lane) {
#pragma unroll
    for (int r = 0; r < 16; ++r) { re[r] = 0.f; im[r] = 0.f; }
    if (lane == 0) re[0] = 1.f;
}

// ---------------- staggered main circuit ----------------
// Every layer is a commuting set: rings (XX/YY products commute mutually),
// single-qubit layers act on disjoint qubits. ODD waves run the DS-heavy
// fused pair LAST instead of FIRST -> co-resident waves' DS bursts offset.

template<bool ODD>
__device__ void run_circuit(float (&re)[16], float (&im)[16],
                            const float* __restrict__ GC, const float* __restrict__ GS,
                            const float* __restrict__ UB, int lane) {
#define RING_L(base, YYf) \
    if constexpr (!ODD) g_ring2(re, im, GC[(base)+1], GS[(base)+1], GC[(base)+9], GS[(base)+9], YYf, lane); \
    g_xy<2, 3, YYf>(re, im, GC[(base)+2], GS[(base)+2], lane); \
    g_xy<3, 4, YYf>(re, im, GC[(base)+3], GS[(base)+3], lane); \
    g_xy<4, 5, YYf>(re, im, GC[(base)+4], GS[(base)+4], lane); \
    g_xy<5, 6, YYf>(re, im, GC[(base)+5], GS[(base)+5], lane); \
    g_xy<6, 7, YYf>(re, im, GC[(base)+6], GS[(base)+6], lane); \
    g_xy<7, 8, YYf>(re, im, GC[(base)+7], GS[(base)+7], lane); \
    g_xy<8, 9, YYf>(re, im, GC[(base)+8], GS[(base)+8], lane); \
    g_xy<0, 1, YYf>(re, im, GC[(base)+0], GS[(base)+0], lane); \
    if constexpr (ODD) g_ring2(re, im, GC[(base)+1], GS[(base)+1], GC[(base)+9], GS[(base)+9], YYf, lane);

#define CD_L(base) \
    if constexpr (!ODD) g_ry2_01(re, im, GC[(base)], GS[(base)], GC[(base)+1], GS[(base)+1], lane); \
    g_ry<2>(re, im, GC[(base)+2], GS[(base)+2], lane); \
    g_ry<3>(re, im, GC[(base)+3], GS[(base)+3], lane); \
    g_ry<4>(re, im, GC[(base)+4], GS[(base)+4], lane); \
    g_ry<5>(re, im, GC[(base)+5], GS[(base)+5], lane); \
    g_ry<6>(re, im, GC[(base)+6], GS[(base)+6], lane); \
    g_ry<7>(re, im, GC[(base)+7], GS[(base)+7], lane); \
    g_ry<8>(re, im, GC[(base)+8], GS[(base)+8], lane); \
    g_ry<9>(re, im, GC[(base)+9], GS[(base)+9], lane); \
    if constexpr (ODD) g_ry2_01(re, im, GC[(base)], GS[(base)], GC[(base)+1], GS[(base)+1], lane);

    RING_L(0, false)
    CD_L(10)
    RING_L(20, true)

    if constexpr (!ODD) g_u2_01(re, im, &UB[0], &UB[8], lane);
    g_u1<2>(re, im, &UB[16], lane);
    g_u1<3>(re, im, &UB[24], lane);
    g_u1<4>(re, im, &UB[32], lane);
    g_u1<5>(re, im, &UB[40], lane);
    g_u1<6>(re, im, &UB[48], lane);
    g_u1<7>(re, im, &UB[56], lane);
    g_u1<8>(re, im, &UB[64], lane);
    g_u1<9>(re, im, &UB[72], lane);
    if constexpr (ODD) g_u2_01(re, im, &UB[0], &UB[8], lane);

    RING_L(30, false)
    CD_L(40)
    RING_L(50, true)
#undef RING_L
#undef CD_L
}

// ---------------- branch circuits (r12, verified) ----------------

__device__ void branch_gating(const float* __restrict__ gb,
                              const float* __restrict__ b1,
                              const float* __restrict__ W2, const float* __restrict__ b2,
                              const float* __restrict__ w1p, const float* __restrict__ w2p,
                              const float* __restrict__ Wout, const float* __restrict__ bout,
                              float* __restrict__ vbr, float* __restrict__ ws_c, int lane) {
    const float w1v = w1p[0], w2v = w2p[0];
    float bias = 0.f;
    if (lane < 30) {
        float v = 0.f;
        for (int k = 0; k < 30; ++k) v = fmaf(Wout[k], W2[k * 30 + lane], v);
        vbr[lane] = w2v * v;
        bias = Wout[lane] * (w1v * b1[lane] + w2v * b2[lane]);
    }

    float re[16], im[16];
    init_state(re, im, lane);
    for (int L = 0; L < 2; ++L) {
        const int g0 = L * 30;
        {
            float c0_, s0_, c1_, s1_;
            __sincosf(0.5f * gb[g0 + 0], &s0_, &c0_);
            __sincosf(0.5f * gb[g0 + 1], &s1_, &c1_);
            g_rx2_01(re, im, c0_, s0_, c1_, s1_, lane);
        }
#define BRX(i) { float s_, c_; __sincosf(0.5f * gb[g0 + i], &s_, &c_); g_rx<i>(re, im, c_, s_, lane); }
        BRX(2) BRX(3) BRX(4) BRX(5) BRX(6) BRX(7) BRX(8) BRX(9)
#undef BRX
#define BCRZ(i) { float s_, c_; __sincosf(0.5f * gb[g0 + 10 + i], &s_, &c_); g_crz<i, i + 1>(re, im, c_, s_, lane); }
        ALLQ9(BCRZ)
#undef BCRZ
        {
            float c0_, s0_, c1_, s1_;
            __sincosf(0.5f * gb[g0 + 19 + 0], &s0_, &c0_);
            __sincosf(0.5f * gb[g0 + 19 + 1], &s1_, &c1_);
            g_ry2_01(re, im, c0_, s0_, c1_, s1_, lane);
        }
#define BRY(i) { float s_, c_; __sincosf(0.5f * gb[g0 + 19 + i], &s_, &c_); g_ry<i>(re, im, c_, s_, lane); }
        BRY(2) BRY(3) BRY(4) BRY(5) BRY(6) BRY(7) BRY(8) BRY(9)
#undef BRY
        { float s_, c_; __sincosf(0.5f * gb[g0 + 29], &s_, &c_); g_crz<9, 0>(re, im, c_, s_, lane); }
    }

    float oacc = meas_fold(re, im, vbr, lane) + bias;
    oacc = wred(oacc, lane);
    if (lane == 0) ws_c[0] = oacc + bout[0];
}

__device__ void branch_skip(const float* __restrict__ sp,
                            const float* __restrict__ W3, const float* __restrict__ b3v,
                            const float* __restrict__ w3p,
                            const float* __restrict__ Wout,
                            float* __restrict__ ws_c, int lane) {
    float vk = 0.f;
    if (lane < 30) {
        const int q = (lane < 10) ? lane : ((lane < 20) ? lane - 10 : lane - 20);
        float c1, s1, c2, s2, c3, s3;
        __sincosf(0.5f * sp[q],      &s1, &c1);
        __sincosf(0.5f * sp[10 + q], &s2, &c2);
        __sincosf(0.5f * sp[20 + q], &s3, &c3);
        float a2r = c2 * c1, a2i = s2 * s1, b2r = s2 * c1, b2i = -c2 * s1;
        float a3r = fmaf(a2i,  s3, a2r * c3), a3i = fmaf(-a2r, s3, a2i * c3);
        float b3r = fmaf(-b2i, s3, b2r * c3), b3i = fmaf( b2r, s3, b2i * c3);
        float m;
        if (lane < 10)      m = 2.f * (a3r * b3r + a3i * b3i);
        else if (lane < 20) m = 2.f * (a3r * b3i - a3i * b3r);
        else                m = (a3r * a3r + a3i * a3i) - (b3r * b3r + b3i * b3i);
        float v = 0.f;
        for (int k = 0; k < 30; ++k) v = fmaf(Wout[k], W3[k * 30 + lane], v);
        vk = w3p[0] * fmaf(m, v, Wout[lane] * b3v[lane]);
    }
    vk = wred(vk, lane);
    if (lane == 0) ws_c[0] = vk;
}

// ---------------- main kernel ----------------

__global__ void __launch_bounds__(TPB) k_main(
    const float* __restrict__ x, const float* __restrict__ Wp,
    const float* __restrict__ bp_, const float* __restrict__ qb,
    const float* __restrict__ bpar, const float* __restrict__ cpar, const float* __restrict__ dtpar,
    const float* __restrict__ gb, const float* __restrict__ sp,
    const float* __restrict__ W1, const float* __restrict__ b1,
    const float* __restrict__ W2, const float* __restrict__ b2,
    const float* __restrict__ W3, const float* __restrict__ b3,
    const float* __restrict__ w1p, const float* __restrict__ w2p, const float* __restrict__ w3p,
    const float* __restrict__ Wout, const float* __restrict__ bout,
    float* __restrict__ ws, int B) {

    const int wv = threadIdx.x >> 6, lane = threadIdx.x & 63;

    __shared__ float vbr[32];

    if (wv == 4) {
        if (blockIdx.x == 0) {
            branch_gating(gb, b1, W2, b2, w1p, w2p, Wout, bout, vbr, ws + B, lane);
            if (gridDim.x == 1) branch_skip(sp, W3, b3, w3p, Wout, ws + B + 1, lane);
        } else if (blockIdx.x == 1) {
            branch_skip(sp, W3, b3, w3p, Wout, ws + B + 1, lane);
        }
        return;
    }

    const int b = blockIdx.x * 4 + wv;
    const int bb = (b < B) ? b : (B - 1);

    __shared__ float proj[4][80];
    __shared__ float ac1[4][10], as1[4][10], ac2[4][10], as2[4][10];
    __shared__ float gc[4][60], gs[4][60];
    __shared__ float ub[4][80];
    __shared__ float uraw[4][32], uu[4][32];

    // ---- projection (16-lane groups, 4 rows/pass) ----
    const int sub = lane & 15, grp = lane >> 4;
    float4 xv[4];
    {
        const float* xr = x + (size_t)bb * 256 + sub * 16;
#pragma unroll
        for (int j = 0; j < 4; ++j) xv[j] = reinterpret_cast<const float4*>(xr)[j];
    }
#pragma unroll 4
    for (int p = 0; p < 20; ++p) {
        const int row = p * 4 + grp;
        const float* wr = Wp + (size_t)row * 256 + sub * 16;
        float acc = 0.f;
#pragma unroll
        for (int j = 0; j < 4; ++j) {
            float4 w4 = reinterpret_cast<const float4*>(wr)[j];
            acc = fmaf(xv[j].x, w4.x, acc); acc = fmaf(xv[j].y, w4.y, acc);
            acc = fmaf(xv[j].z, w4.z, acc); acc = fmaf(xv[j].w, w4.w, acc);
        }
        acc += lx<1>(acc, lane); acc += lx<2>(acc, lane);
        acc += lx<4>(acc, lane); acc += lx<8>(acc, lane);
        if (sub == 0) proj[wv][row] = acc;
    }

    // ---- angle prep ----
    {
#define DO_ANGLE(IDX) { \
        const int idx = (IDX); \
        float ang = TWO_PI_F / (1.f + __expf(-(proj[wv][idx] + bp_[idx]))) + qb[idx]; \
        const int l = (idx >= 40) ? 1 : 0; \
        const int p = idx - 40 * l; \
        float s_, c_; \
        if (p < 10) { \
            __sincosf(0.5f * ang, &s_, &c_); \
            if (l == 0) { ac1[wv][p] = c_; as1[wv][p] = s_; } \
            else        { ac2[wv][p] = c_; as2[wv][p] = s_; } \
        } else if (p < 20) { \
            __sincosf(0.5f * ang, &s_, &c_); \
            gc[wv][l * 30 + p - 10] = c_; gs[wv][l * 30 + p - 10] = s_; \
        } else if (p < 30) { \
            __sincosf(0.5f * (ang + bpar[p - 20]), &s_, &c_); \
            gc[wv][l * 30 + 10 + p - 20] = c_; gs[wv][l * 30 + 10 + p - 20] = s_; \
        } else { \
            __sincosf(0.5f * ang, &s_, &c_); \
            gc[wv][l * 30 + 20 + p - 30] = c_; gs[wv][l * 30 + 20 + p - 30] = s_; \
        } }
        DO_ANGLE(lane)
        if (lane < 16) DO_ANGLE(64 + lane)
#undef DO_ANGLE

        if (lane < 30) {
            float ut = 0.f;
            for (int k = 0; k < 30; ++k) ut = fmaf(Wout[k], W1[k * 30 + lane], ut);
            uraw[wv][lane] = w1p[0] * ut;
        }
        if (lane < 10) {
            float ca = ac2[wv][lane], sa = as2[wv][lane];
            float cg2, sg2, cd2, sd2;
            __sincosf(0.5f * cpar[lane],  &sg2, &cg2);
            __sincosf(0.5f * dtpar[lane], &sd2, &cd2);
            float A = ca * cd2, Bv = sa * sd2;
            float C = -sa * cd2, D = -ca * sd2;
            float E = sa * cd2,  F = -ca * sd2;
            float G = ca * cd2,  H = -sa * sd2;
            float* U = &ub[wv][lane * 8];
            U[0] = cg2 * A + sg2 * Bv;  U[1] = cg2 * Bv - sg2 * A;
            U[2] = cg2 * C - sg2 * D;   U[3] = sg2 * C + cg2 * D;
            U[4] = cg2 * E + sg2 * F;   U[5] = cg2 * F - sg2 * E;
            U[6] = cg2 * G - sg2 * H;   U[7] = sg2 * G + cg2 * H;

            float cg, sgf, cd, sdf;
            __sincosf(cpar[lane],  &sgf, &cg);
            __sincosf(dtpar[lane], &sdf, &cd);
            float uX = uraw[wv][lane], uY = uraw[wv][10 + lane], uZ = uraw[wv][20 + lane];
            uu[wv][lane]      =  uX * cg + uY * cd * sgf + uZ * sdf * sgf;
            uu[wv][10 + lane] = -uX * sgf + uY * cd * cg + uZ * sdf * cg;
            uu[wv][20 + lane] = -uY * sdf + uZ * cd;
        }
    }

    // ---- product initial state ----
    float re[16], im[16];
    {
        const float* AC = ac1[wv]; const float* AS = as1[wv];
        float pl = ((lane >> 5) & 1) ? AS[0] : AC[0];
        pl *= ((lane >> 4) & 1) ? AS[1] : AC[1];
        pl *= ((lane >> 3) & 1) ? AS[2] : AC[2];
        pl *= ((lane >> 2) & 1) ? AS[3] : AC[3];
        pl *= ((lane >> 1) & 1) ? AS[4] : AC[4];
        pl *= ( lane       & 1) ? AS[5] : AC[5];
#pragma unroll
        for (int r = 0; r < 16; ++r) {
            float p = ((r >> 3) & 1) ? AS[6] : AC[6];
            p *= ((r >> 2) & 1) ? AS[7] : AC[7];
            p *= ((r >> 1) & 1) ? AS[8] : AC[8];
            p *= ( r       & 1) ? AS[9] : AC[9];
            re[r] = pl * p; im[r] = 0.f;
        }
    }

    // ---- staggered fused circuit ----
    if (wv & 1) run_circuit<true>(re, im, gc[wv], gs[wv], ub[wv], lane);
    else        run_circuit<false>(re, im, gc[wv], gs[wv], ub[wv], lane);

    // ---- folded measurement ----
    float oacc = meas_fold(re, im, uu[wv], lane);
    oacc = wred(oacc, lane);
    if (lane == 0 && b < B) ws[b] = oacc;
}

__global__ void k_out(const float* __restrict__ ws, float* __restrict__ out, int B) {
    int i = blockIdx.x * blockDim.x + threadIdx.x;
    if (i < B) out[i] = ws[i] + ws[B] + ws[B + 1];
}

extern "C" void kernel_launch(void* const* d_in, const int* in_sizes, int n_in,
                              void* d_out, int out_size, void* d_ws, size_t ws_size,
                              hipStream_t stream) {
    const float* x         = (const float*)d_in[0];
    const float* W_proj    = (const float*)d_in[1];
    const float* b_proj    = (const float*)d_in[2];
    const float* qlcu_base = (const float*)d_in[3];
    const float* gate_base = (const float*)d_in[4];
    const float* skip_base = (const float*)d_in[5];
    const float* b_params  = (const float*)d_in[6];
    const float* c_params  = (const float*)d_in[7];
    const float* dt_params = (const float*)d_in[8];
    const float* W1    = (const float*)d_in[9];
    const float* b1    = (const float*)d_in[10];
    const float* W2    = (const float*)d_in[11];
    const float* b2    = (const float*)d_in[12];
    const float* W3    = (const float*)d_in[13];
    const float* b3    = (const float*)d_in[14];
    const float* w1    = (const float*)d_in[15];
    const float* w2    = (const float*)d_in[16];
    const float* w3    = (const float*)d_in[17];
    const float* W_out = (const float*)d_in[18];
    const float* b_out = (const float*)d_in[19];
    float* out = (float*)d_out;
    float* ws  = (float*)d_ws;

    const int B = in_sizes[0] / 256;   // FEATURE_DIM = 256
    const int nb = (B + 3) / 4;        // 512 for B=2048 (exact)

    hipLaunchKernelGGL(k_main, dim3(nb), dim3(TPB), 0, stream,
                       x, W_proj, b_proj, qlcu_base, b_params, c_params, dt_params,
                       gate_base, skip_base, W1, b1, W2, b2, W3, b3, w1, w2, w3,
                       W_out, b_out, ws, B);
    hipLaunchKernelGGL(k_out, dim3((B + 255) / 256), dim3(256), 0, stream, ws, out, B);
}

// Round 16
// 48.690 us; speedup vs baseline: 1.1520x; 1.1476x over previous
//
#include <hip/hip_runtime.h>
#include <math.h>

#define TPB 320
#define TWO_PI_F 6.283185307179586f

// State layout: one wave (64 lanes) holds 1024 amplitudes.
// s = (lane << 4) | r,  r = 0..15 in registers re[16], im[16].
// Qubit w -> state bit (9-w).  w <= 5: lane bit (5-w).  w >= 6: local bit (9-w).

#define ALLQ(OP) OP(0) OP(1) OP(2) OP(3) OP(4) OP(5) OP(6) OP(7) OP(8) OP(9)
#define ALLQ9(OP) OP(0) OP(1) OP(2) OP(3) OP(4) OP(5) OP(6) OP(7) OP(8)

template<int CTRL>
__device__ __forceinline__ float dppmv(float v) {
    return __builtin_bit_cast(float,
        __builtin_amdgcn_update_dpp(0, __builtin_bit_cast(int, v), CTRL, 0xF, 0xF, true));
}

template<int LM>
__device__ __forceinline__ float lx(float v, int lane) {
    (void)lane;
    if constexpr (LM == 1)       return dppmv<0xB1>(v);
    else if constexpr (LM == 2)  return dppmv<0x4E>(v);
    else if constexpr (LM == 3)  return dppmv<0x1B>(v);
    else if constexpr (LM == 4)  return dppmv<0x1B>(dppmv<0x141>(v));   // 7^3
    else if constexpr (LM == 6)  return dppmv<0xB1>(dppmv<0x141>(v));   // 7^1
    else if constexpr (LM == 8)  return dppmv<0x128>(v);                // ror 8
    else if constexpr (LM == 12) return dppmv<0x1B>(dppmv<0x140>(v));   // 15^3
    else                         return __shfl_xor(v, LM);              // 16,24,32,48,56
}

template<int W>
__device__ __forceinline__ int qbit(int lane, int r) {
    if constexpr (W <= 5) return (lane >> (5 - W)) & 1;
    else                  return (r >> (9 - W)) & 1;
}

// ---------------- single gates (prefetch-then-compute) ----------------

template<int W>
__device__ __forceinline__ void g_ry(float (&re)[16], float (&im)[16], float c, float s, int lane) {
    if constexpr (W <= 5) {
        constexpr int LM = 1 << (5 - W);
        const float ss = ((lane >> (5 - W)) & 1) ? s : -s;
        float pr[16], pi[16];
#pragma unroll
        for (int r = 0; r < 16; ++r) { pr[r] = lx<LM>(re[r], lane); pi[r] = lx<LM>(im[r], lane); }
#pragma unroll
        for (int r = 0; r < 16; ++r) {
            re[r] = fmaf(ss, pr[r], c * re[r]);
            im[r] = fmaf(ss, pi[r], c * im[r]);
        }
    } else {
        constexpr int MK = 1 << (9 - W);
#pragma unroll
        for (int r = 0; r < 16; ++r) {
            if ((r & MK) == 0) {
                const int r1 = r | MK;
                float r0 = re[r], i0 = im[r], r1v = re[r1], i1 = im[r1];
                re[r]  = fmaf(-s, r1v, c * r0);
                im[r]  = fmaf(-s, i1,  c * i0);
                re[r1] = fmaf( s, r0,  c * r1v);
                im[r1] = fmaf( s, i0,  c * i1);
            }
        }
    }
}

template<int W>
__device__ __forceinline__ void g_rx(float (&re)[16], float (&im)[16], float c, float s, int lane) {
    if constexpr (W <= 5) {
        constexpr int LM = 1 << (5 - W);
        float pr[16], pi[16];
#pragma unroll
        for (int r = 0; r < 16; ++r) { pr[r] = lx<LM>(re[r], lane); pi[r] = lx<LM>(im[r], lane); }
#pragma unroll
        for (int r = 0; r < 16; ++r) {
            re[r] = fmaf( s, pi[r], c * re[r]);
            im[r] = fmaf(-s, pr[r], c * im[r]);
        }
    } else {
        constexpr int MK = 1 << (9 - W);
#pragma unroll
        for (int r = 0; r < 16; ++r) {
            if ((r & MK) == 0) {
                const int r1 = r | MK;
                float r0 = re[r], i0 = im[r], r1v = re[r1], i1 = im[r1];
                re[r]  = fmaf( s, i1,  c * r0);
                im[r]  = fmaf(-s, r1v, c * i0);
                re[r1] = fmaf( s, i0,  c * r1v);
                im[r1] = fmaf(-s, r0,  c * i1);
            }
        }
    }
}

template<int C, int T>
__device__ __forceinline__ void g_crz(float (&re)[16], float (&im)[16], float c, float s, int lane) {
#pragma unroll
    for (int r = 0; r < 16; ++r) {
        const int cb = qbit<C>(lane, r);
        const int tb = qbit<T>(lane, r);
        const float cc  = cb ? c : 1.f;
        const float sp2 = cb ? (tb ? s : -s) : 0.f;
        float rr = re[r], ii = im[r];
        re[r] = cc * rr - sp2 * ii;
        im[r] = cc * ii + sp2 * rr;
    }
}

template<int A, int Bq, bool YY>
__device__ __forceinline__ void g_xy(float (&re)[16], float (&im)[16], float c, float s, int lane) {
    constexpr int bpA = 9 - A, bpB = 9 - Bq;
    constexpr int LM   = ((bpA >= 4) ? (1 << (bpA - 4)) : 0) | ((bpB >= 4) ? (1 << (bpB - 4)) : 0);
    constexpr int LOCM = ((bpA < 4) ? (1 << bpA) : 0) | ((bpB < 4) ? (1 << bpB) : 0);
    float pr[16], pi[16];
#pragma unroll
    for (int r = 0; r < 16; ++r) {
        float vr = re[r ^ LOCM], vi = im[r ^ LOCM];
        if constexpr (LM != 0) { pr[r] = lx<LM>(vr, lane); pi[r] = lx<LM>(vi, lane); }
        else                   { pr[r] = vr; pi[r] = vi; }
    }
#pragma unroll
    for (int r = 0; r < 16; ++r) {
        float sg;
        if constexpr (YY) {
            const int bA = qbit<A>(lane, r);
            const int bB = qbit<Bq>(lane, r);
            sg = (bA == bB) ? -s : s;
        } else sg = s;
        float rr = re[r], ii = im[r];
        re[r] = fmaf( sg, pi[r], c * rr);
        im[r] = fmaf(-sg, pr[r], c * ii);
    }
}

// general 1-qubit gate U = [[u00,u01],[u10,u11]] complex, entries in U[0..7]
template<int W>
__device__ __forceinline__ void g_u1(float (&re)[16], float (&im)[16], const float* U, int lane) {
    const float u00r=U[0], u00i=U[1], u01r=U[2], u01i=U[3];
    const float u10r=U[4], u10i=U[5], u11r=U[6], u11i=U[7];
    if constexpr (W <= 5) {
        constexpr int LM = 1 << (5 - W);
        const int side = (lane >> (5 - W)) & 1;
        const float aR = side ? u11r : u00r, aI = side ? u11i : u00i;
        const float bR = side ? u10r : u01r, bI = side ? u10i : u01i;
        float pr[16], pi[16];
#pragma unroll
        for (int r = 0; r < 16; ++r) { pr[r] = lx<LM>(re[r], lane); pi[r] = lx<LM>(im[r], lane); }
#pragma unroll
        for (int r = 0; r < 16; ++r) {
            float rr = re[r], ii = im[r];
            float nr = aR * rr; nr = fmaf(-aI, ii, nr); nr = fmaf(bR, pr[r], nr); nr = fmaf(-bI, pi[r], nr);
            float ni = aR * ii; ni = fmaf( aI, rr, ni); ni = fmaf(bR, pi[r], ni); ni = fmaf( bI, pr[r], ni);
            re[r] = nr; im[r] = ni;
        }
    } else {
        constexpr int MK = 1 << (9 - W);
#pragma unroll
        for (int r = 0; r < 16; ++r) {
            if ((r & MK) == 0) {
                const int r1 = r | MK;
                float r0 = re[r], i0 = im[r], r1v = re[r1], i1 = im[r1];
                float a = u00r*r0; a = fmaf(-u00i, i0, a); a = fmaf(u01r, r1v, a); a = fmaf(-u01i, i1, a);
                float b = u00r*i0; b = fmaf( u00i, r0, b); b = fmaf(u01r, i1,  b); b = fmaf( u01i, r1v, b);
                float c = u10r*r0; c = fmaf(-u10i, i0, c); c = fmaf(u11r, r1v, c); c = fmaf(-u11i, i1, c);
                float d = u10r*i0; d = fmaf( u10i, r0, d); d = fmaf(u11r, i1,  d); d = fmaf( u11i, r1v, d);
                re[r] = a; im[r] = b; re[r1] = c; im[r1] = d;
            }
        }
    }
}

// ---------------- fused pair gates ----------------

__device__ __forceinline__ void g_ry2_01(float (&re)[16], float (&im)[16],
                                         float c0, float s0, float c1, float s1, int lane) {
    float ar[16], ai[16], br[16], bi[16], cr2[16], ci2[16];
#pragma unroll
    for (int r = 0; r < 16; ++r) { ar[r] = lx<32>(re[r], lane); ai[r] = lx<32>(im[r], lane); }
#pragma unroll
    for (int r = 0; r < 16; ++r) { br[r] = lx<16>(re[r], lane); bi[r] = lx<16>(im[r], lane); }
#pragma unroll
    for (int r = 0; r < 16; ++r) { cr2[r] = lx<48>(re[r], lane); ci2[r] = lx<48>(im[r], lane); }
    const float sg0 = ((lane >> 5) & 1) ? s0 : -s0;
    const float sg1 = ((lane >> 4) & 1) ? s1 : -s1;
    const float k0 = c0 * c1, k1 = c1 * sg0, k2 = c0 * sg1, k3 = sg0 * sg1;
#pragma unroll
    for (int r = 0; r < 16; ++r) {
        float o_r = k0 * re[r];
        o_r = fmaf(k1, ar[r], o_r); o_r = fmaf(k2, br[r], o_r); o_r = fmaf(k3, cr2[r], o_r);
        float o_i = k0 * im[r];
        o_i = fmaf(k1, ai[r], o_i); o_i = fmaf(k2, bi[r], o_i); o_i = fmaf(k3, ci2[r], o_i);
        re[r] = o_r; im[r] = o_i;
    }
}

__device__ __forceinline__ void g_rx2_01(float (&re)[16], float (&im)[16],
                                         float c0, float s0, float c1, float s1, int lane) {
    float ar[16], ai[16], br[16], bi[16], cr2[16], ci2[16];
#pragma unroll
    for (int r = 0; r < 16; ++r) { ar[r] = lx<32>(re[r], lane); ai[r] = lx<32>(im[r], lane); }
#pragma unroll
    for (int r = 0; r < 16; ++r) { br[r] = lx<16>(re[r], lane); bi[r] = lx<16>(im[r], lane); }
#pragma unroll
    for (int r = 0; r < 16; ++r) { cr2[r] = lx<48>(re[r], lane); ci2[r] = lx<48>(im[r], lane); }
    const float k0 = c0 * c1, kA = c1 * s0, kB = c0 * s1, kC = s0 * s1;
#pragma unroll
    for (int r = 0; r < 16; ++r) {
        float rr = re[r], ii = im[r];
        float o_r = k0 * rr;
        o_r = fmaf(kA, ai[r], o_r); o_r = fmaf(kB, bi[r], o_r); o_r = fmaf(-kC, cr2[r], o_r);
        float o_i = k0 * ii;
        o_i = fmaf(-kA, ar[r], o_i); o_i = fmaf(-kB, br[r], o_i); o_i = fmaf(-kC, ci2[r], o_i);
        re[r] = o_r; im[r] = o_i;
    }
}

__device__ __forceinline__ void g_u2_01(float (&re)[16], float (&im)[16],
                                        const float* U0, const float* U1, int lane) {
    const int b0 = (lane >> 5) & 1, b1 = (lane >> 4) & 1;
    const float u0o_r = U0[(b0*2+b0)*2],       u0o_i = U0[(b0*2+b0)*2+1];
    const float u0f_r = U0[(b0*2+(b0^1))*2],   u0f_i = U0[(b0*2+(b0^1))*2+1];
    const float u1o_r = U1[(b1*2+b1)*2],       u1o_i = U1[(b1*2+b1)*2+1];
    const float u1f_r = U1[(b1*2+(b1^1))*2],   u1f_i = U1[(b1*2+(b1^1))*2+1];
    const float K00r = u0o_r*u1o_r - u0o_i*u1o_i, K00i = u0o_r*u1o_i + u0o_i*u1o_r;
    const float K01r = u0o_r*u1f_r - u0o_i*u1f_i, K01i = u0o_r*u1f_i + u0o_i*u1f_r;
    const float K10r = u0f_r*u1o_r - u0f_i*u1o_i, K10i = u0f_r*u1o_i + u0f_i*u1o_r;
    const float K11r = u0f_r*u1f_r - u0f_i*u1f_i, K11i = u0f_r*u1f_i + u0f_i*u1f_r;
    float ar[16], ai[16], br[16], bi[16], cr2[16], ci2[16];
#pragma unroll
    for (int r = 0; r < 16; ++r) { ar[r] = lx<32>(re[r], lane); ai[r] = lx<32>(im[r], lane); }
#pragma unroll
    for (int r = 0; r < 16; ++r) { br[r] = lx<16>(re[r], lane); bi[r] = lx<16>(im[r], lane); }
#pragma unroll
    for (int r = 0; r < 16; ++r) { cr2[r] = lx<48>(re[r], lane); ci2[r] = lx<48>(im[r], lane); }
#pragma unroll
    for (int r = 0; r < 16; ++r) {
        float rr = re[r], ii = im[r];
        float o_r = K00r * rr;         o_r = fmaf(-K00i, ii, o_r);
        o_r = fmaf(K01r, br[r], o_r);  o_r = fmaf(-K01i, bi[r], o_r);
        o_r = fmaf(K10r, ar[r], o_r);  o_r = fmaf(-K10i, ai[r], o_r);
        o_r = fmaf(K11r, cr2[r], o_r); o_r = fmaf(-K11i, ci2[r], o_r);
        float o_i = K00r * ii;         o_i = fmaf(K00i, rr, o_i);
        o_i = fmaf(K01r, bi[r], o_i);  o_i = fmaf(K01i, br[r], o_i);
        o_i = fmaf(K10r, ai[r], o_i);  o_i = fmaf(K10i, ar[r], o_i);
        o_i = fmaf(K11r, ci2[r], o_i); o_i = fmaf(K11i, cr2[r], o_i);
        re[r] = o_r; im[r] = o_i;
    }
}

// fused ring pair: gate a = XY(1,2) [LM 24], gate b = XY(9,0) [LM 32, LOCM 1].
__device__ __forceinline__ void g_ring2(float (&re)[16], float (&im)[16],
                                        float ca, float sa, float cb, float sb,
                                        bool yy, int lane) {
    float ar[16], ai[16], br[16], bi[16], cr2[16], ci2[16];
#pragma unroll
    for (int r = 0; r < 16; ++r) { ar[r] = lx<24>(re[r], lane); ai[r] = lx<24>(im[r], lane); }
#pragma unroll
    for (int r = 0; r < 16; ++r) { br[r] = lx<32>(re[r ^ 1], lane); bi[r] = lx<32>(im[r ^ 1], lane); }
#pragma unroll
    for (int r = 0; r < 16; ++r) { cr2[r] = lx<56>(re[r ^ 1], lane); ci2[r] = lx<56>(im[r ^ 1], lane); }
    float ka, kb0, kb1, kab0, kab1;
    if (yy) {
        const bool ea = (((lane >> 4) & 1) == ((lane >> 3) & 1));
        const float sga = ea ? -sa : sa;
        const int b0l = (lane >> 5) & 1;
        const float sgb0 = (0 == b0l) ? -sb : sb;
        const float sgb1 = (1 == b0l) ? -sb : sb;
        ka = cb * sga; kb0 = ca * sgb0; kb1 = ca * sgb1;
        kab0 = sga * sgb0; kab1 = sga * sgb1;
    } else {
        ka = cb * sa; kb0 = kb1 = ca * sb; kab0 = kab1 = sa * sb;
    }
    const float k0 = ca * cb;
#pragma unroll
    for (int r = 0; r < 16; ++r) {
        const float kb  = (r & 1) ? kb1  : kb0;
        const float kab = (r & 1) ? kab1 : kab0;
        float rr = re[r], ii = im[r];
        float o_r = k0 * rr;
        o_r = fmaf(ka, ai[r], o_r); o_r = fmaf(kb, bi[r], o_r); o_r = fmaf(-kab, cr2[r], o_r);
        float o_i = k0 * ii;
        o_i = fmaf(-ka, ar[r], o_i); o_i = fmaf(-kb, br[r], o_i); o_i = fmaf(-kab, ci2[r], o_i);
        re[r] = o_r; im[r] = o_i;
    }
}

// full-wave reduce (sum)
__device__ __forceinline__ float wred(float v, int lane) {
    v += lx<1>(v, lane); v += lx<2>(v, lane); v += lx<4>(v, lane);
    v += lx<8>(v, lane); v += lx<16>(v, lane); v += lx<32>(v, lane);
    return v;
}

// ---------------- folded measurement (shared by main + gating) ----------------
__device__ float meas_fold(const float (&re)[16], const float (&im)[16],
                           const float* __restrict__ V, int lane) {
    float oacc = 0.f;
    float q0r[16], q0i[16], q1r[16], q1i[16];
#pragma unroll
    for (int r = 0; r < 16; ++r) { q0r[r] = lx<32>(re[r], lane); q0i[r] = lx<32>(im[r], lane); }
#pragma unroll
    for (int r = 0; r < 16; ++r) { q1r[r] = lx<16>(re[r], lane); q1i[r] = lx<16>(im[r], lane); }

    float n2[16], n2s = 0.f;
#pragma unroll
    for (int r = 0; r < 16; ++r) { n2[r] = fmaf(re[r], re[r], im[r] * im[r]); n2s += n2[r]; }

#define M_LANE(w, LM_) { \
        float pr[16], pi[16]; \
        _Pragma("unroll") \
        for (int r = 0; r < 16; ++r) { pr[r] = lx<LM_>(re[r], lane); pi[r] = lx<LM_>(im[r], lane); } \
        float xa = 0.f, ya = 0.f; \
        _Pragma("unroll") \
        for (int r = 0; r < 16; ++r) { \
            xa = fmaf(re[r], pr[r], xa); xa = fmaf(im[r], pi[r], xa); \
            ya = fmaf(re[r], pi[r], ya); ya = fmaf(-im[r], pr[r], ya); \
        } \
        const float sg = ((lane >> (5 - w)) & 1) ? -1.f : 1.f; \
        oacc = fmaf(xa, V[w], oacc); \
        oacc = fmaf(sg * ya, V[10 + w], oacc); \
        oacc = fmaf(sg * n2s, V[20 + w], oacc); }
    M_LANE(2, 8) M_LANE(3, 4) M_LANE(4, 2) M_LANE(5, 1)
#undef M_LANE

#define M_REG(w, MK) { \
        float xa = 0.f, ya = 0.f, za = 0.f; \
        _Pragma("unroll") \
        for (int r = 0; r < 16; ++r) { \
            if ((r & MK) == 0) { \
                const int r1 = r | MK; \
                xa = fmaf(re[r], re[r1], xa); xa = fmaf(im[r], im[r1], xa); \
                ya = fmaf(re[r], im[r1], ya); ya = fmaf(-im[r], re[r1], ya); \
                za += n2[r] - n2[r1]; \
            } } \
        oacc = fmaf(2.f * xa, V[w], oacc); \
        oacc = fmaf(2.f * ya, V[10 + w], oacc); \
        oacc = fmaf(za, V[20 + w], oacc); }
    M_REG(6, 8) M_REG(7, 4) M_REG(8, 2) M_REG(9, 1)
#undef M_REG

    {
        float xa = 0.f, ya = 0.f;
#pragma unroll
        for (int r = 0; r < 16; ++r) {
            xa = fmaf(re[r], q0r[r], xa); xa = fmaf(im[r], q0i[r], xa);
            ya = fmaf(re[r], q0i[r], ya); ya = fmaf(-im[r], q0r[r], ya);
        }
        const float sg = ((lane >> 5) & 1) ? -1.f : 1.f;
        oacc = fmaf(xa, V[0], oacc);
        oacc = fmaf(sg * ya, V[10], oacc);
        oacc = fmaf(sg * n2s, V[20], oacc);
    }
    {
        float xa = 0.f, ya = 0.f;
#pragma unroll
        for (int r = 0; r < 16; ++r) {
            xa = fmaf(re[r], q1r[r], xa); xa = fmaf(im[r], q1i[r], xa);
            ya = fmaf(re[r], q1i[r], ya); ya = fmaf(-im[r], q1r[r], ya);
        }
        const float sg = ((lane >> 4) & 1) ? -1.f : 1.f;
        oacc = fmaf(xa, V[1], oacc);
        oacc = fmaf(sg * ya, V[11], oacc);
        oacc = fmaf(sg * n2s, V[21], oacc);
    }
    return oacc;
}

__device__ __forceinline__ void init_state(float (&re)[16], float (&im)[16], int lane) {
#pragma unroll
    for (int r = 0; r < 16; ++r) { re[r] = 0.f; im[r] = 0.f; }
    if (lane == 0) re[0] = 1.f;
}

// ---------------- branch circuits ----------------

__device__ void branch_gating(const float* __restrict__ gb,
                              const float* __restrict__ b1,
                              const float* __restrict__ W2, const float* __restrict__ b2,
                              const float* __restrict__ w1p, const float* __restrict__ w2p,
                              const float* __restrict__ Wout, const float* __restrict__ bout,
                              float* __restrict__ vbr, float* __restrict__ ws_c, int lane) {
    const float w1v = w1p[0], w2v = w2p[0];
    float bias = 0.f;
    if (lane < 30) {
        float v = 0.f;
        for (int k = 0; k < 30; ++k) v = fmaf(Wout[k], W2[k * 30 + lane], v);
        vbr[lane] = w2v * v;
        bias = Wout[lane] * (w1v * b1[lane] + w2v * b2[lane]);
    }

    float re[16], im[16];
    init_state(re, im, lane);
    for (int L = 0; L < 2; ++L) {
        const int g0 = L * 30;
        {
            float c0_, s0_, c1_, s1_;
            __sincosf(0.5f * gb[g0 + 0], &s0_, &c0_);
            __sincosf(0.5f * gb[g0 + 1], &s1_, &c1_);
            g_rx2_01(re, im, c0_, s0_, c1_, s1_, lane);
        }
#define BRX(i) { float s_, c_; __sincosf(0.5f * gb[g0 + i], &s_, &c_); g_rx<i>(re, im, c_, s_, lane); }
        BRX(2) BRX(3) BRX(4) BRX(5) BRX(6) BRX(7) BRX(8) BRX(9)
#undef BRX
#define BCRZ(i) { float s_, c_; __sincosf(0.5f * gb[g0 + 10 + i], &s_, &c_); g_crz<i, i + 1>(re, im, c_, s_, lane); }
        ALLQ9(BCRZ)
#undef BCRZ
        {
            float c0_, s0_, c1_, s1_;
            __sincosf(0.5f * gb[g0 + 19 + 0], &s0_, &c0_);
            __sincosf(0.5f * gb[g0 + 19 + 1], &s1_, &c1_);
            g_ry2_01(re, im, c0_, s0_, c1_, s1_, lane);
        }
#define BRY(i) { float s_, c_; __sincosf(0.5f * gb[g0 + 19 + i], &s_, &c_); g_ry<i>(re, im, c_, s_, lane); }
        BRY(2) BRY(3) BRY(4) BRY(5) BRY(6) BRY(7) BRY(8) BRY(9)
#undef BRY
        { float s_, c_; __sincosf(0.5f * gb[g0 + 29], &s_, &c_); g_crz<9, 0>(re, im, c_, s_, lane); }
    }

    float oacc = meas_fold(re, im, vbr, lane) + bias;
    oacc = wred(oacc, lane);
    if (lane == 0) ws_c[0] = oacc + bout[0];
}

__device__ void branch_skip(const float* __restrict__ sp,
                            const float* __restrict__ W3, const float* __restrict__ b3v,
                            const float* __restrict__ w3p,
                            const float* __restrict__ Wout,
                            float* __restrict__ ws_c, int lane) {
    float vk = 0.f;
    if (lane < 30) {
        const int q = (lane < 10) ? lane : ((lane < 20) ? lane - 10 : lane - 20);
        float c1, s1, c2, s2, c3, s3;
        __sincosf(0.5f * sp[q],      &s1, &c1);
        __sincosf(0.5f * sp[10 + q], &s2, &c2);
        __sincosf(0.5f * sp[20 + q], &s3, &c3);
        float a2r = c2 * c1, a2i = s2 * s1, b2r = s2 * c1, b2i = -c2 * s1;
        float a3r = fmaf(a2i,  s3, a2r * c3), a3i = fmaf(-a2r, s3, a2i * c3);
        float b3r = fmaf(-b2i, s3, b2r * c3), b3i = fmaf( b2r, s3, b2i * c3);
        float m;
        if (lane < 10)      m = 2.f * (a3r * b3r + a3i * b3i);
        else if (lane < 20) m = 2.f * (a3r * b3i - a3i * b3r);
        else                m = (a3r * a3r + a3i * a3i) - (b3r * b3r + b3i * b3i);
        float v = 0.f;
        for (int k = 0; k < 30; ++k) v = fmaf(Wout[k], W3[k * 30 + lane], v);
        vk = w3p[0] * fmaf(m, v, Wout[lane] * b3v[lane]);
    }
    vk = wred(vk, lane);
    if (lane == 0) ws_c[0] = vk;
}

// ---------------- main kernel ----------------

__global__ void __launch_bounds__(TPB) k_main(
    const float* __restrict__ x, const float* __restrict__ Wp,
    const float* __restrict__ bp_, const float* __restrict__ qb,
    const float* __restrict__ bpar, const float* __restrict__ cpar, const float* __restrict__ dtpar,
    const float* __restrict__ gb, const float* __restrict__ sp,
    const float* __restrict__ W1, const float* __restrict__ b1,
    const float* __restrict__ W2, const float* __restrict__ b2,
    const float* __restrict__ W3, const float* __restrict__ b3,
    const float* __restrict__ w1p, const float* __restrict__ w2p, const float* __restrict__ w3p,
    const float* __restrict__ Wout, const float* __restrict__ bout,
    float* __restrict__ ws, int B) {

    const int wv = threadIdx.x >> 6, lane = threadIdx.x & 63;

    __shared__ float vbr[32];

    if (wv == 4) {
        if (blockIdx.x == 0) {
            branch_gating(gb, b1, W2, b2, w1p, w2p, Wout, bout, vbr, ws + B, lane);
            if (gridDim.x == 1) branch_skip(sp, W3, b3, w3p, Wout, ws + B + 1, lane);
        } else if (blockIdx.x == 1) {
            branch_skip(sp, W3, b3, w3p, Wout, ws + B + 1, lane);
        }
        return;
    }

    const int b = blockIdx.x * 4 + wv;
    const int bb = (b < B) ? b : (B - 1);

    __shared__ float proj[4][80];
    __shared__ float ac1[4][10], as1[4][10], ac2[4][10], as2[4][10];
    __shared__ float gc[4][60], gs[4][60];
    __shared__ float ub[4][80];
    __shared__ float uraw[4][32], uu[4][32];

    // ---- projection (16-lane groups, 4 rows/pass) ----
    const int sub = lane & 15, grp = lane >> 4;
    float4 xv[4];
    {
        const float* xr = x + (size_t)bb * 256 + sub * 16;
#pragma unroll
        for (int j = 0; j < 4; ++j) xv[j] = reinterpret_cast<const float4*>(xr)[j];
    }
#pragma unroll 4
    for (int p = 0; p < 20; ++p) {
        const int row = p * 4 + grp;
        const float* wr = Wp + (size_t)row * 256 + sub * 16;
        float acc = 0.f;
#pragma unroll
        for (int j = 0; j < 4; ++j) {
            float4 w4 = reinterpret_cast<const float4*>(wr)[j];
            acc = fmaf(xv[j].x, w4.x, acc); acc = fmaf(xv[j].y, w4.y, acc);
            acc = fmaf(xv[j].z, w4.z, acc); acc = fmaf(xv[j].w, w4.w, acc);
        }
        acc += lx<1>(acc, lane); acc += lx<2>(acc, lane);
        acc += lx<4>(acc, lane); acc += lx<8>(acc, lane);
        if (sub == 0) proj[wv][row] = acc;
    }

    // ---- angle prep ----
    {
#define DO_ANGLE(IDX) { \
        const int idx = (IDX); \
        float ang = TWO_PI_F / (1.f + __expf(-(proj[wv][idx] + bp_[idx]))) + qb[idx]; \
        const int l = (idx >= 40) ? 1 : 0; \
        const int p = idx - 40 * l; \
        float s_, c_; \
        if (p < 10) { \
            __sincosf(0.5f * ang, &s_, &c_); \
            if (l == 0) { ac1[wv][p] = c_; as1[wv][p] = s_; } \
            else        { ac2[wv][p] = c_; as2[wv][p] = s_; } \
        } else if (p < 20) { \
            __sincosf(0.5f * ang, &s_, &c_); \
            gc[wv][l * 30 + p - 10] = c_; gs[wv][l * 30 + p - 10] = s_; \
        } else if (p < 30) { \
            __sincosf(0.5f * (ang + bpar[p - 20]), &s_, &c_); \
            gc[wv][l * 30 + 10 + p - 20] = c_; gs[wv][l * 30 + 10 + p - 20] = s_; \
        } else { \
            __sincosf(0.5f * ang, &s_, &c_); \
            gc[wv][l * 30 + 20 + p - 30] = c_; gs[wv][l * 30 + 20 + p - 30] = s_; \
        } }
        DO_ANGLE(lane)
        if (lane < 16) DO_ANGLE(64 + lane)
#undef DO_ANGLE

        if (lane < 30) {
            float ut = 0.f;
            for (int k = 0; k < 30; ++k) ut = fmaf(Wout[k], W1[k * 30 + lane], ut);
            uraw[wv][lane] = w1p[0] * ut;
        }
        if (lane < 10) {
            float ca = ac2[wv][lane], sa = as2[wv][lane];
            float cg2, sg2, cd2, sd2;
            __sincosf(0.5f * cpar[lane],  &sg2, &cg2);
            __sincosf(0.5f * dtpar[lane], &sd2, &cd2);
            float A = ca * cd2, Bv = sa * sd2;
            float C = -sa * cd2, D = -ca * sd2;
            float E = sa * cd2,  F = -ca * sd2;
            float G = ca * cd2,  H = -sa * sd2;
            float* U = &ub[wv][lane * 8];
            U[0] = cg2 * A + sg2 * Bv;  U[1] = cg2 * Bv - sg2 * A;
            U[2] = cg2 * C - sg2 * D;   U[3] = sg2 * C + cg2 * D;
            U[4] = cg2 * E + sg2 * F;   U[5] = cg2 * F - sg2 * E;
            U[6] = cg2 * G - sg2 * H;   U[7] = sg2 * G + cg2 * H;

            float cg, sgf, cd, sdf;
            __sincosf(cpar[lane],  &sgf, &cg);
            __sincosf(dtpar[lane], &sdf, &cd);
            float uX = uraw[wv][lane], uY = uraw[wv][10 + lane], uZ = uraw[wv][20 + lane];
            uu[wv][lane]      =  uX * cg + uY * cd * sgf + uZ * sdf * sgf;
            uu[wv][10 + lane] = -uX * sgf + uY * cd * cg + uZ * sdf * cg;
            uu[wv][20 + lane] = -uY * sdf + uZ * cd;
        }
    }

    // ---- product initial state ----
    float re[16], im[16];
    {
        const float* AC = ac1[wv]; const float* AS = as1[wv];
        float pl = ((lane >> 5) & 1) ? AS[0] : AC[0];
        pl *= ((lane >> 4) & 1) ? AS[1] : AC[1];
        pl *= ((lane >> 3) & 1) ? AS[2] : AC[2];
        pl *= ((lane >> 2) & 1) ? AS[3] : AC[3];
        pl *= ((lane >> 1) & 1) ? AS[4] : AC[4];
        pl *= ( lane       & 1) ? AS[5] : AC[5];
#pragma unroll
        for (int r = 0; r < 16; ++r) {
            float p = ((r >> 3) & 1) ? AS[6] : AC[6];
            p *= ((r >> 2) & 1) ? AS[7] : AC[7];
            p *= ((r >> 1) & 1) ? AS[8] : AC[8];
            p *= ( r       & 1) ? AS[9] : AC[9];
            re[r] = pl * p; im[r] = 0.f;
        }
    }

    // ---- fused circuit ----
    const float* GC = gc[wv]; const float* GS = gs[wv];

#define RING(base, YYf) \
    g_ring2(re, im, GC[(base)+1], GS[(base)+1], GC[(base)+9], GS[(base)+9], YYf, lane); \
    g_xy<2, 3, YYf>(re, im, GC[(base)+2], GS[(base)+2], lane); \
    g_xy<3, 4, YYf>(re, im, GC[(base)+3], GS[(base)+3], lane); \
    g_xy<4, 5, YYf>(re, im, GC[(base)+4], GS[(base)+4], lane); \
    g_xy<5, 6, YYf>(re, im, GC[(base)+5], GS[(base)+5], lane); \
    g_xy<6, 7, YYf>(re, im, GC[(base)+6], GS[(base)+6], lane); \
    g_xy<7, 8, YYf>(re, im, GC[(base)+7], GS[(base)+7], lane); \
    g_xy<8, 9, YYf>(re, im, GC[(base)+8], GS[(base)+8], lane); \
    g_xy<0, 1, YYf>(re, im, GC[(base)+0], GS[(base)+0], lane);

    RING(0, false)
    g_ry2_01(re, im, GC[10], GS[10], GC[11], GS[11], lane);
#define G_CD1(i) g_ry<i>(re, im, GC[10 + i], GS[10 + i], lane);
    G_CD1(2) G_CD1(3) G_CD1(4) G_CD1(5) G_CD1(6) G_CD1(7) G_CD1(8) G_CD1(9)
#undef G_CD1
    RING(20, true)
    g_u2_01(re, im, &ub[wv][0], &ub[wv][8], lane);
#define G_UB(i) g_u1<i>(re, im, &ub[wv][i * 8], lane);
    G_UB(2) G_UB(3) G_UB(4) G_UB(5) G_UB(6) G_UB(7) G_UB(8) G_UB(9)
#undef G_UB
    RING(30, false)
    g_ry2_01(re, im, GC[40], GS[40], GC[41], GS[41], lane);
#define G_CD2(i) g_ry<i>(re, im, GC[40 + i], GS[40 + i], lane);
    G_CD2(2) G_CD2(3) G_CD2(4) G_CD2(5) G_CD2(6) G_CD2(7) G_CD2(8) G_CD2(9)
#undef G_CD2
    RING(50, true)
#undef RING

    // ---- folded measurement ----
    float oacc = meas_fold(re, im, uu[wv], lane);
    oacc = wred(oacc, lane);
    if (lane == 0 && b < B) ws[b] = oacc;
}

__global__ void k_out(const float* __restrict__ ws, float* __restrict__ out, int B) {
    int i = blockIdx.x * blockDim.x + threadIdx.x;
    if (i < B) out[i] = ws[i] + ws[B] + ws[B + 1];
}

extern "C" void kernel_launch(void* const* d_in, const int* in_sizes, int n_in,
                              void* d_out, int out_size, void* d_ws, size_t ws_size,
                              hipStream_t stream) {
    const float* x         = (const float*)d_in[0];
    const float* W_proj    = (const float*)d_in[1];
    const float* b_proj    = (const float*)d_in[2];
    const float* qlcu_base = (const float*)d_in[3];
    const float* gate_base = (const float*)d_in[4];
    const float* skip_base = (const float*)d_in[5];
    const float* b_params  = (const float*)d_in[6];
    const float* c_params  = (const float*)d_in[7];
    const float* dt_params = (const float*)d_in[8];
    const float* W1    = (const float*)d_in[9];
    const float* b1    = (const float*)d_in[10];
    const float* W2    = (const float*)d_in[11];
    const float* b2    = (const float*)d_in[12];
    const float* W3    = (const float*)d_in[13];
    const float* b3    = (const float*)d_in[14];
    const float* w1    = (const float*)d_in[15];
    const float* w2    = (const float*)d_in[16];
    const float* w3    = (const float*)d_in[17];
    const float* W_out = (const float*)d_in[18];
    const float* b_out = (const float*)d_in[19];
    float* out = (float*)d_out;
    float* ws  = (float*)d_ws;

    const int B = in_sizes[0] / 256;   // FEATURE_DIM = 256
    const int nb = (B + 3) / 4;        // 512 for B=2048 (exact)

    hipLaunchKernelGGL(k_main, dim3(nb), dim3(TPB), 0, stream,
                       x, W_proj, b_proj, qlcu_base, b_params, c_params, dt_params,
                       gate_base, skip_base, W1, b1, W2, b2, W3, b3, w1, w2, w3,
                       W_out, b_out, ws, B);
    hipLaunchKernelGGL(k_out, dim3((B + 255) / 256), dim3(256), 0, stream, ws, out, B);
}